// Round 1
// baseline (1104.811 us; speedup 1.0000x reference)
//
#include <hip/hip_runtime.h>

typedef _Float16 half8 __attribute__((ext_vector_type(8)));
typedef _Float16 hv4 __attribute__((ext_vector_type(4)));
typedef float fv4 __attribute__((ext_vector_type(4)));
typedef unsigned int uv4 __attribute__((ext_vector_type(4)));

// ---------------------------------------------------------------- LayerNorm
__global__ __launch_bounds__(256) void ln_rows(const float* __restrict__ in,
                                               const float* __restrict__ g,
                                               const float* __restrict__ bb,
                                               _Float16* __restrict__ out, int ncols) {
  __shared__ float sm[8];
  int row = blockIdx.x, t = threadIdx.x;
  const float* rp = in + (size_t)row * ncols;
  int nv = ncols >> 10;  // 1024-wide chunks (1 or 2)
  fv4 v[2];
  float s1 = 0.f, s2 = 0.f;
#pragma unroll
  for (int c = 0; c < 2; ++c)
    if (c < nv) {
      v[c] = *(const fv4*)(rp + c * 1024 + t * 4);
#pragma unroll
      for (int j = 0; j < 4; ++j) { s1 += v[c][j]; s2 += v[c][j] * v[c][j]; }
    }
#pragma unroll
  for (int off = 32; off > 0; off >>= 1) { s1 += __shfl_xor(s1, off, 64); s2 += __shfl_xor(s2, off, 64); }
  int w = t >> 6;
  if ((t & 63) == 0) { sm[w] = s1; sm[4 + w] = s2; }
  __syncthreads();
  s1 = sm[0] + sm[1] + sm[2] + sm[3];
  s2 = sm[4] + sm[5] + sm[6] + sm[7];
  float inv = 1.0f / (float)ncols;
  float mu = s1 * inv;
  float var = s2 * inv - mu * mu;
  float rstd = rsqrtf(var + 1e-5f);
#pragma unroll
  for (int c = 0; c < 2; ++c)
    if (c < nv) {
      int col = c * 1024 + t * 4;
      fv4 gg = *(const fv4*)(g + col);
      fv4 bv = *(const fv4*)(bb + col);
      hv4 o;
#pragma unroll
      for (int j = 0; j < 4; ++j) o[j] = (_Float16)(((v[c][j] - mu) * rstd) * gg[j] + bv[j]);
      *(hv4*)(out + (size_t)row * ncols + col) = o;
    }
}

// ---------------------------------------------------------------- fp32 -> fp16 cast
__global__ __launch_bounds__(256) void cast_f16(const float* __restrict__ in,
                                                _Float16* __restrict__ out, int n) {
  int i = (blockIdx.x * 256 + threadIdx.x) << 2;
  if (i < n) {
    fv4 f = *(const fv4*)(in + i);
    hv4 h;
#pragma unroll
    for (int j = 0; j < 4; ++j) h[j] = (_Float16)f[j];
    *(hv4*)(out + i) = h;
  }
}

// ---------------------------------------------------------------- entmax-1.5 tau solve
// One wave per score row (2048 fp32). Solves sum((x - tau)+^2) = 1 by Newton from
// tau=-1 (monotone from below for convex f), then closed-form refinement on the
// support set. Writes c = 0.5*rowmax + tau so that w = (max(0, 0.5*s - c))^2.
__global__ __launch_bounds__(256) void entmax_crow(const float* __restrict__ scores,
                                                   float* __restrict__ crow) {
  int row = blockIdx.x * 4 + (threadIdx.x >> 6);
  int l = threadIdx.x & 63;
  const fv4* sp = (const fv4*)(scores + (size_t)row * 2048);
  fv4 x[8];
#pragma unroll
  for (int i = 0; i < 8; ++i) x[i] = sp[i * 64 + l];
  float m = x[0][0];
#pragma unroll
  for (int i = 0; i < 8; ++i)
#pragma unroll
    for (int j = 0; j < 4; ++j) m = fmaxf(m, x[i][j]);
#pragma unroll
  for (int off = 32; off > 0; off >>= 1) m = fmaxf(m, __shfl_xor(m, off, 64));
#pragma unroll
  for (int i = 0; i < 8; ++i)
#pragma unroll
    for (int j = 0; j < 4; ++j) x[i][j] = (x[i][j] - m) * 0.5f;

  float tau = -1.0f;
  for (int it = 0; it < 12; ++it) {
    float f = 0.f, gs = 0.f;
#pragma unroll
    for (int i = 0; i < 8; ++i)
#pragma unroll
      for (int j = 0; j < 4; ++j) {
        float d = fmaxf(x[i][j] - tau, 0.f);
        f = fmaf(d, d, f);
        gs += d;
      }
#pragma unroll
    for (int off = 32; off > 0; off >>= 1) { f += __shfl_xor(f, off, 64); gs += __shfl_xor(gs, off, 64); }
    tau += (f - 1.0f) / (2.0f * gs);  // gs >= -tau >= ~0.02, safe
    tau = fminf(fmaxf(tau, -1.0f), 0.0f);
  }
  // refinement: exact tau for the detected support
  float cnt = 0.f, s1 = 0.f, s2 = 0.f;
#pragma unroll
  for (int i = 0; i < 8; ++i)
#pragma unroll
    for (int j = 0; j < 4; ++j)
      if (x[i][j] > tau) { cnt += 1.f; s1 += x[i][j]; s2 = fmaf(x[i][j], x[i][j], s2); }
#pragma unroll
  for (int off = 32; off > 0; off >>= 1) {
    cnt += __shfl_xor(cnt, off, 64);
    s1 += __shfl_xor(s1, off, 64);
    s2 += __shfl_xor(s2, off, 64);
  }
  float mean = s1 / cnt;
  float ss = s2 - s1 * mean;  // = cnt*(meansq - mean^2)
  float tstar = mean - sqrtf(fmaxf((1.0f - ss) / cnt, 0.0f));
  if (l == 0) crow[row] = 0.5f * m + tstar;
}

// ---------------------------------------------------------------- generic NT GEMM
// C[M,N] = alpha * A[M,K] @ B[N,K]^T.  128x128 tile, 4 waves of 4x4 16x16x32 f16 MFMA.
// aMode 0: A is fp16 (optionally hi+lo split with 3-pass MFMA for ~fp32 accuracy)
// aMode 1: A is fp32 scores with fused entmax weight transform w=(max(0,s/2-c))^2
// outMode 0: fp16   1: fp32   2: fp16 hi+lo split store
struct GemmParams {
  const _Float16* A;
  const _Float16* Alo;
  const float* A32;
  const float* crow;
  const _Float16* B;
  const _Float16* Blo;
  _Float16* C16;
  _Float16* C16lo;
  float* C32;
  const float* log_beta;
  int K, lda, ldb;
  long long aSB, aSH;
  long long crowSB, crowSH;
  long long bSH;
  long long cSB, cSH, cOsR, cOsC;
  int aMode, split, alphaMode, outMode;
};

__global__ __launch_bounds__(256) void gemm_nt(GemmParams p) {
  __shared__ __align__(16) _Float16 As[128 * 32];
  __shared__ __align__(16) _Float16 Bs[128 * 32];
  __shared__ __align__(16) _Float16 Asl[128 * 32];
  __shared__ __align__(16) _Float16 Bsl[128 * 32];
  int t = threadIdx.x;
  int m0 = blockIdx.y * 128, n0 = blockIdx.x * 128;
  int z = blockIdx.z, bidx = z >> 3, h = z & 7;
  const _Float16* pA = p.A ? p.A + bidx * p.aSB + h * p.aSH : nullptr;
  const _Float16* pAl = p.Alo ? p.Alo + bidx * p.aSB + h * p.aSH : nullptr;
  const float* pA32 = p.A32 ? p.A32 + bidx * p.aSB + h * p.aSH : nullptr;
  const float* pc = p.crow ? p.crow + bidx * p.crowSB + h * p.crowSH : nullptr;
  const _Float16* pB = p.B + h * p.bSH;
  const _Float16* pBl = p.Blo ? p.Blo + h * p.bSH : nullptr;

  fv4 acc[4][4] = {};
  int wv = t >> 6, l = t & 63, quad = l >> 4, lr = l & 15;
  int wm = (wv >> 1) * 64, wn = (wv & 1) * 64;

  for (int k0 = 0; k0 < p.K; k0 += 32) {
#pragma unroll
    for (int v = 0; v < 2; ++v) {
      int vv = t + v * 256;
      int r = vv >> 2, kc = (vv & 3) << 3;
      if (p.aMode == 0) {
        *(uv4*)&As[r * 32 + kc] = *(const uv4*)(pA + (size_t)(m0 + r) * p.lda + k0 + kc);
        if (p.split)
          *(uv4*)&Asl[r * 32 + kc] = *(const uv4*)(pAl + (size_t)(m0 + r) * p.lda + k0 + kc);
      } else {
        const float* sp = pA32 + (size_t)(m0 + r) * p.lda + k0 + kc;
        float c0 = pc[m0 + r];
        fv4 f0 = *(const fv4*)sp, f1 = *(const fv4*)(sp + 4);
        half8 hh;
#pragma unroll
        for (int j = 0; j < 4; ++j) {
          float d0 = fmaxf(f0[j] * 0.5f - c0, 0.f);
          hh[j] = (_Float16)(d0 * d0);
          float d1 = fmaxf(f1[j] * 0.5f - c0, 0.f);
          hh[4 + j] = (_Float16)(d1 * d1);
        }
        *(half8*)&As[r * 32 + kc] = hh;
      }
      *(uv4*)&Bs[r * 32 + kc] = *(const uv4*)(pB + (size_t)(n0 + r) * p.ldb + k0 + kc);
      if (p.split)
        *(uv4*)&Bsl[r * 32 + kc] = *(const uv4*)(pBl + (size_t)(n0 + r) * p.ldb + k0 + kc);
    }
    __syncthreads();
    half8 ah[4], bh[4];
#pragma unroll
    for (int mi = 0; mi < 4; ++mi) ah[mi] = *(const half8*)&As[(wm + mi * 16 + lr) * 32 + quad * 8];
#pragma unroll
    for (int ni = 0; ni < 4; ++ni) bh[ni] = *(const half8*)&Bs[(wn + ni * 16 + lr) * 32 + quad * 8];
#pragma unroll
    for (int mi = 0; mi < 4; ++mi)
#pragma unroll
      for (int ni = 0; ni < 4; ++ni)
        acc[mi][ni] = __builtin_amdgcn_mfma_f32_16x16x32_f16(ah[mi], bh[ni], acc[mi][ni], 0, 0, 0);
    if (p.split) {
      half8 al[4], bl[4];
#pragma unroll
      for (int mi = 0; mi < 4; ++mi) al[mi] = *(const half8*)&Asl[(wm + mi * 16 + lr) * 32 + quad * 8];
#pragma unroll
      for (int ni = 0; ni < 4; ++ni) bl[ni] = *(const half8*)&Bsl[(wn + ni * 16 + lr) * 32 + quad * 8];
#pragma unroll
      for (int mi = 0; mi < 4; ++mi)
#pragma unroll
        for (int ni = 0; ni < 4; ++ni) {
          acc[mi][ni] = __builtin_amdgcn_mfma_f32_16x16x32_f16(al[mi], bh[ni], acc[mi][ni], 0, 0, 0);
          acc[mi][ni] = __builtin_amdgcn_mfma_f32_16x16x32_f16(ah[mi], bl[ni], acc[mi][ni], 0, 0, 0);
        }
    }
    __syncthreads();
  }

  float alpha = p.alphaMode ? __expf(p.log_beta[h]) : 1.0f;
  long long cOff = (long long)bidx * p.cSB + (long long)h * p.cSH;
#pragma unroll
  for (int mi = 0; mi < 4; ++mi)
#pragma unroll
    for (int ni = 0; ni < 4; ++ni) {
      int row = m0 + wm + mi * 16 + quad * 4;
      int col = n0 + wn + ni * 16 + lr;
#pragma unroll
      for (int r = 0; r < 4; ++r) {
        float val = acc[mi][ni][r] * alpha;
        long long idx = cOff + (long long)(row + r) * p.cOsR + (long long)col * p.cOsC;
        if (p.outMode == 1) {
          p.C32[idx] = val;
        } else if (p.outMode == 0) {
          p.C16[idx] = (_Float16)val;
        } else {
          _Float16 hi = (_Float16)val;
          p.C16[idx] = hi;
          p.C16lo[idx] = (_Float16)(val - (float)hi);
        }
      }
    }
}

// ---------------------------------------------------------------- host
extern "C" void kernel_launch(void* const* d_in, const int* in_sizes, int n_in,
                              void* d_out, int out_size, void* d_ws, size_t ws_size,
                              hipStream_t stream) {
  const float* hidden = (const float*)d_in[0];   // (2,1024,2048)
  const float* memory = (const float*)d_in[1];   // (2048,1024)
  const float* Wq = (const float*)d_in[2];       // (1024,2048)
  const float* Wk = (const float*)d_in[3];       // (1024,1024)
  const float* Wv = (const float*)d_in[4];       // (1024,1024)
  const float* Wo = (const float*)d_in[5];       // (2048,1024)
  const float* log_beta = (const float*)d_in[6]; // (8,)
  const float* g_state = (const float*)d_in[7];
  const float* b_state = (const float*)d_in[8];
  const float* g_mem = (const float*)d_in[9];
  const float* b_mem = (const float*)d_in[10];

  char* w = (char*)d_ws;
  auto alloc = [&](size_t bytes) {
    char* r = w;
    w += (bytes + 255) & ~(size_t)255;
    return r;
  };
  _Float16* wq16 = (_Float16*)alloc(2097152 * 2);
  _Float16* wk16 = (_Float16*)alloc(1048576 * 2);
  _Float16* wv16 = (_Float16*)alloc(1048576 * 2);
  _Float16* wo16 = (_Float16*)alloc(2097152 * 2);
  _Float16* lnh16 = (_Float16*)alloc(4194304 * 2);
  _Float16* mn16 = (_Float16*)alloc(2097152 * 2);
  _Float16* kph = (_Float16*)alloc(2097152 * 2);   // K proj hi (n, h*128+d)
  _Float16* kpl = (_Float16*)alloc(2097152 * 2);   // K proj lo
  _Float16* vt16 = (_Float16*)alloc(2097152 * 2);  // V^T (h*128+d, n)
  _Float16* xih = (_Float16*)alloc(2097152 * 2);   // xi hi, layout (b*S+s, h*128+d)
  _Float16* xil = (_Float16*)alloc(2097152 * 2);   // xi lo
  float* crow = (float*)alloc(16384 * 4);
  float* scores = (float*)alloc((size_t)33554432 * 4);  // (b,h,s,n) fp32, 128 MB

  ln_rows<<<2048, 256, 0, stream>>>(hidden, g_state, b_state, lnh16, 2048);
  ln_rows<<<2048, 256, 0, stream>>>(memory, g_mem, b_mem, mn16, 1024);
  cast_f16<<<2048, 256, 0, stream>>>(Wq, wq16, 2097152);
  cast_f16<<<1024, 256, 0, stream>>>(Wk, wk16, 1048576);
  cast_f16<<<1024, 256, 0, stream>>>(Wv, wv16, 1048576);
  cast_f16<<<2048, 256, 0, stream>>>(Wo, wo16, 2097152);

  // Q = ln(hidden) @ Wq^T  -> xi (split store)
  {
    GemmParams p{};
    p.A = lnh16; p.lda = 2048;
    p.B = wq16; p.ldb = 2048;
    p.K = 2048;
    p.C16 = xih; p.C16lo = xil; p.outMode = 2;
    p.cOsR = 1024; p.cOsC = 1;
    gemm_nt<<<dim3(8, 16, 1), 256, 0, stream>>>(p);
  }
  // K proj (split store, row-major (n, hd))
  {
    GemmParams p{};
    p.A = mn16; p.lda = 1024;
    p.B = wk16; p.ldb = 1024;
    p.K = 1024;
    p.C16 = kph; p.C16lo = kpl; p.outMode = 2;
    p.cOsR = 1024; p.cOsC = 1;
    gemm_nt<<<dim3(8, 16, 1), 256, 0, stream>>>(p);
  }
  // V proj (plain, transposed store -> (hd, n))
  {
    GemmParams p{};
    p.A = mn16; p.lda = 1024;
    p.B = wv16; p.ldb = 1024;
    p.K = 1024;
    p.C16 = vt16; p.outMode = 0;
    p.cOsR = 1; p.cOsC = 2048;
    gemm_nt<<<dim3(8, 16, 1), 256, 0, stream>>>(p);
  }

  for (int step = 0; step < 3; ++step) {
    // scores = beta_h * xi @ K^T   (split inputs, fp32 out)
    {
      GemmParams p{};
      p.A = xih; p.Alo = xil; p.split = 1;
      p.lda = 1024; p.aSB = 1048576; p.aSH = 128;
      p.B = kph; p.Blo = kpl; p.ldb = 1024; p.bSH = 128;
      p.K = 128;
      p.alphaMode = 1; p.log_beta = log_beta;
      p.C32 = scores; p.outMode = 1;
      p.cSB = 16777216; p.cSH = 2097152;
      p.cOsR = 2048; p.cOsC = 1;
      gemm_nt<<<dim3(16, 8, 16), 256, 0, stream>>>(p);
    }
    entmax_crow<<<4096, 256, 0, stream>>>(scores, crow);
    // xi = entmax_w(scores) @ V   (fused w transform on A staging, split store)
    {
      GemmParams p{};
      p.aMode = 1;
      p.A32 = scores; p.crow = crow;
      p.lda = 2048; p.aSB = 16777216; p.aSH = 2097152;
      p.crowSB = 8192; p.crowSH = 1024;
      p.B = vt16; p.ldb = 2048; p.bSH = 262144;
      p.K = 2048;
      p.C16 = xih; p.C16lo = xil; p.outMode = 2;
      p.cSB = 1048576; p.cSH = 128;
      p.cOsR = 1024; p.cOsC = 1;
      gemm_nt<<<dim3(1, 8, 16), 256, 0, stream>>>(p);
    }
  }

  // out = xi @ Wo^T  (fp32 out)
  {
    GemmParams p{};
    p.A = xih; p.lda = 1024;
    p.B = wo16; p.ldb = 1024;
    p.K = 1024;
    p.C32 = (float*)d_out; p.outMode = 1;
    p.cOsR = 2048; p.cOsC = 1;
    gemm_nt<<<dim3(16, 16, 1), 256, 0, stream>>>(p);
  }
}

// Round 2
// 1018.228 us; speedup vs baseline: 1.0850x; 1.0850x over previous
//
#include <hip/hip_runtime.h>

typedef _Float16 half8 __attribute__((ext_vector_type(8)));
typedef _Float16 hv4 __attribute__((ext_vector_type(4)));
typedef float fv4 __attribute__((ext_vector_type(4)));
typedef unsigned int uv4 __attribute__((ext_vector_type(4)));

#define LDSS 40  // LDS tile row stride in halves (80 B): banks spread, 16B-aligned

// ---------------------------------------------------------------- LayerNorm
__global__ __launch_bounds__(256) void ln_rows(const float* __restrict__ in,
                                               const float* __restrict__ g,
                                               const float* __restrict__ bb,
                                               _Float16* __restrict__ out, int ncols) {
  __shared__ float sm[8];
  int row = blockIdx.x, t = threadIdx.x;
  const float* rp = in + (size_t)row * ncols;
  int nv = ncols >> 10;  // 1024-wide chunks (1 or 2)
  fv4 v[2];
  float s1 = 0.f, s2 = 0.f;
#pragma unroll
  for (int c = 0; c < 2; ++c)
    if (c < nv) {
      v[c] = *(const fv4*)(rp + c * 1024 + t * 4);
#pragma unroll
      for (int j = 0; j < 4; ++j) { s1 += v[c][j]; s2 += v[c][j] * v[c][j]; }
    }
#pragma unroll
  for (int off = 32; off > 0; off >>= 1) { s1 += __shfl_xor(s1, off, 64); s2 += __shfl_xor(s2, off, 64); }
  int w = t >> 6;
  if ((t & 63) == 0) { sm[w] = s1; sm[4 + w] = s2; }
  __syncthreads();
  s1 = sm[0] + sm[1] + sm[2] + sm[3];
  s2 = sm[4] + sm[5] + sm[6] + sm[7];
  float inv = 1.0f / (float)ncols;
  float mu = s1 * inv;
  float var = s2 * inv - mu * mu;
  float rstd = rsqrtf(var + 1e-5f);
#pragma unroll
  for (int c = 0; c < 2; ++c)
    if (c < nv) {
      int col = c * 1024 + t * 4;
      fv4 gg = *(const fv4*)(g + col);
      fv4 bv = *(const fv4*)(bb + col);
      hv4 o;
#pragma unroll
      for (int j = 0; j < 4; ++j) o[j] = (_Float16)(((v[c][j] - mu) * rstd) * gg[j] + bv[j]);
      *(hv4*)(out + (size_t)row * ncols + col) = o;
    }
}

// ---------------------------------------------------------------- fp32 -> fp16 cast
__global__ __launch_bounds__(256) void cast_f16(const float* __restrict__ in,
                                                _Float16* __restrict__ out, int n) {
  int i = (blockIdx.x * 256 + threadIdx.x) << 2;
  if (i < n) {
    fv4 f = *(const fv4*)(in + i);
    hv4 h;
#pragma unroll
    for (int j = 0; j < 4; ++j) h[j] = (_Float16)f[j];
    *(hv4*)(out + i) = h;
  }
}

// ---------------------------------------------------------------- zero fp32
__global__ __launch_bounds__(256) void zero_f32(float* __restrict__ p, int n) {
  int i = (blockIdx.x * 256 + threadIdx.x) << 2;
  if (i < n) *(fv4*)(p + i) = fv4{0.f, 0.f, 0.f, 0.f};
}

// ---------------------------------------------------------------- fp32 -> hi/lo fp16 split
__global__ __launch_bounds__(256) void split_f16(const float* __restrict__ in,
                                                 _Float16* __restrict__ hi,
                                                 _Float16* __restrict__ lo, int n) {
  int i = (blockIdx.x * 256 + threadIdx.x) << 2;
  if (i < n) {
    fv4 f = *(const fv4*)(in + i);
    hv4 h, l;
#pragma unroll
    for (int j = 0; j < 4; ++j) {
      h[j] = (_Float16)f[j];
      l[j] = (_Float16)(f[j] - (float)h[j]);
    }
    *(hv4*)(hi + i) = h;
    *(hv4*)(lo + i) = l;
  }
}

// ---------------------------------------------------------------- entmax-1.5 tau solve
// One wave per score row (2048 fp32). Newton from tau=-1 + closed-form refinement.
// Writes c = 0.5*rowmax + tau so that w = (max(0, 0.5*s - c))^2.
__global__ __launch_bounds__(256) void entmax_crow(const float* __restrict__ scores,
                                                   float* __restrict__ crow) {
  int row = blockIdx.x * 4 + (threadIdx.x >> 6);
  int l = threadIdx.x & 63;
  const fv4* sp = (const fv4*)(scores + (size_t)row * 2048);
  fv4 x[8];
#pragma unroll
  for (int i = 0; i < 8; ++i) x[i] = sp[i * 64 + l];
  float m = x[0][0];
#pragma unroll
  for (int i = 0; i < 8; ++i)
#pragma unroll
    for (int j = 0; j < 4; ++j) m = fmaxf(m, x[i][j]);
#pragma unroll
  for (int off = 32; off > 0; off >>= 1) m = fmaxf(m, __shfl_xor(m, off, 64));
#pragma unroll
  for (int i = 0; i < 8; ++i)
#pragma unroll
    for (int j = 0; j < 4; ++j) x[i][j] = (x[i][j] - m) * 0.5f;

  float tau = -1.0f;
  for (int it = 0; it < 12; ++it) {
    float f = 0.f, gs = 0.f;
#pragma unroll
    for (int i = 0; i < 8; ++i)
#pragma unroll
      for (int j = 0; j < 4; ++j) {
        float d = fmaxf(x[i][j] - tau, 0.f);
        f = fmaf(d, d, f);
        gs += d;
      }
#pragma unroll
    for (int off = 32; off > 0; off >>= 1) { f += __shfl_xor(f, off, 64); gs += __shfl_xor(gs, off, 64); }
    tau += (f - 1.0f) / (2.0f * gs);
    tau = fminf(fmaxf(tau, -1.0f), 0.0f);
  }
  float cnt = 0.f, s1 = 0.f, s2 = 0.f;
#pragma unroll
  for (int i = 0; i < 8; ++i)
#pragma unroll
    for (int j = 0; j < 4; ++j)
      if (x[i][j] > tau) { cnt += 1.f; s1 += x[i][j]; s2 = fmaf(x[i][j], x[i][j], s2); }
#pragma unroll
  for (int off = 32; off > 0; off >>= 1) {
    cnt += __shfl_xor(cnt, off, 64);
    s1 += __shfl_xor(s1, off, 64);
    s2 += __shfl_xor(s2, off, 64);
  }
  float mean = s1 / cnt;
  float ss = s2 - s1 * mean;
  float tstar = mean - sqrtf(fmaxf((1.0f - ss) / cnt, 0.0f));
  if (l == 0) crow[row] = 0.5f * m + tstar;
}

// ---------------------------------------------------------------- generic NT GEMM
// C[M,N] = alpha * A[M,K] @ B[N,K]^T.  128x128 tile, 4 waves of 4x4 16x16x32 f16 MFMA.
// aMode 0: A fp16 (optional hi+lo split, 3-pass MFMA)   aMode 1: fp32 scores + fused entmax w
// outMode 0: fp16   1: fp32   2: fp16 hi+lo   3: fp32 atomicAdd (split-K)
// nsplit>1: blockIdx.x = K-chunk (grid.x = nsplit), single N tile (n0 = 0).
struct GemmParams {
  const _Float16* A;
  const _Float16* Alo;
  const float* A32;
  const float* crow;
  const _Float16* B;
  const _Float16* Blo;
  _Float16* C16;
  _Float16* C16lo;
  float* C32;
  const float* log_beta;
  int K, lda, ldb;
  long long aSB, aSH;
  long long crowSB, crowSH;
  long long bSH;
  long long cSB, cSH, cOsR, cOsC;
  int aMode, split, alphaMode, outMode, nsplit;
};

__global__ __launch_bounds__(256) void gemm_nt(GemmParams p) {
  __shared__ __align__(16) _Float16 As[128 * LDSS];
  __shared__ __align__(16) _Float16 Bs[128 * LDSS];
  __shared__ __align__(16) _Float16 Asl[128 * LDSS];
  __shared__ __align__(16) _Float16 Bsl[128 * LDSS];
  int t = threadIdx.x;
  int m0 = blockIdx.y * 128;
  int n0, kbeg, kend;
  if (p.nsplit > 1) {
    n0 = 0;
    int klen = p.K / p.nsplit;
    kbeg = blockIdx.x * klen;
    kend = kbeg + klen;
  } else {
    n0 = blockIdx.x * 128;
    kbeg = 0;
    kend = p.K;
  }
  int z = blockIdx.z, bidx = z >> 3, h = z & 7;
  const _Float16* pA = p.A ? p.A + bidx * p.aSB + h * p.aSH : nullptr;
  const _Float16* pAl = p.Alo ? p.Alo + bidx * p.aSB + h * p.aSH : nullptr;
  const float* pA32 = p.A32 ? p.A32 + bidx * p.aSB + h * p.aSH : nullptr;
  const float* pc = p.crow ? p.crow + bidx * p.crowSB + h * p.crowSH : nullptr;
  const _Float16* pB = p.B + h * p.bSH;
  const _Float16* pBl = p.Blo ? p.Blo + h * p.bSH : nullptr;

  fv4 acc[4][4] = {};
  int wv = t >> 6, l = t & 63, quad = l >> 4, lr = l & 15;
  int wm = (wv >> 1) * 64, wn = (wv & 1) * 64;

  for (int k0 = kbeg; k0 < kend; k0 += 32) {
#pragma unroll
    for (int v = 0; v < 2; ++v) {
      int vv = t + v * 256;
      int r = vv >> 2, kc = (vv & 3) << 3;
      if (p.aMode == 0) {
        *(uv4*)&As[r * LDSS + kc] = *(const uv4*)(pA + (size_t)(m0 + r) * p.lda + k0 + kc);
        if (p.split)
          *(uv4*)&Asl[r * LDSS + kc] = *(const uv4*)(pAl + (size_t)(m0 + r) * p.lda + k0 + kc);
      } else {
        const float* sp = pA32 + (size_t)(m0 + r) * p.lda + k0 + kc;
        float c0 = pc[m0 + r];
        fv4 f0 = *(const fv4*)sp, f1 = *(const fv4*)(sp + 4);
        half8 hh;
#pragma unroll
        for (int j = 0; j < 4; ++j) {
          float d0 = fmaxf(f0[j] * 0.5f - c0, 0.f);
          hh[j] = (_Float16)(d0 * d0);
          float d1 = fmaxf(f1[j] * 0.5f - c0, 0.f);
          hh[4 + j] = (_Float16)(d1 * d1);
        }
        *(half8*)&As[r * LDSS + kc] = hh;
      }
      *(uv4*)&Bs[r * LDSS + kc] = *(const uv4*)(pB + (size_t)(n0 + r) * p.ldb + k0 + kc);
      if (p.split)
        *(uv4*)&Bsl[r * LDSS + kc] = *(const uv4*)(pBl + (size_t)(n0 + r) * p.ldb + k0 + kc);
    }
    __syncthreads();
    half8 ah[4], bh[4];
#pragma unroll
    for (int mi = 0; mi < 4; ++mi) ah[mi] = *(const half8*)&As[(wm + mi * 16 + lr) * LDSS + quad * 8];
#pragma unroll
    for (int ni = 0; ni < 4; ++ni) bh[ni] = *(const half8*)&Bs[(wn + ni * 16 + lr) * LDSS + quad * 8];
#pragma unroll
    for (int mi = 0; mi < 4; ++mi)
#pragma unroll
      for (int ni = 0; ni < 4; ++ni)
        acc[mi][ni] = __builtin_amdgcn_mfma_f32_16x16x32_f16(ah[mi], bh[ni], acc[mi][ni], 0, 0, 0);
    if (p.split) {
      half8 al[4], bl[4];
#pragma unroll
      for (int mi = 0; mi < 4; ++mi) al[mi] = *(const half8*)&Asl[(wm + mi * 16 + lr) * LDSS + quad * 8];
#pragma unroll
      for (int ni = 0; ni < 4; ++ni) bl[ni] = *(const half8*)&Bsl[(wn + ni * 16 + lr) * LDSS + quad * 8];
#pragma unroll
      for (int mi = 0; mi < 4; ++mi)
#pragma unroll
        for (int ni = 0; ni < 4; ++ni) {
          acc[mi][ni] = __builtin_amdgcn_mfma_f32_16x16x32_f16(al[mi], bh[ni], acc[mi][ni], 0, 0, 0);
          acc[mi][ni] = __builtin_amdgcn_mfma_f32_16x16x32_f16(ah[mi], bl[ni], acc[mi][ni], 0, 0, 0);
        }
    }
    __syncthreads();
  }

  float alpha = p.alphaMode ? __expf(p.log_beta[h]) : 1.0f;
  long long cOff = (long long)bidx * p.cSB + (long long)h * p.cSH;
#pragma unroll
  for (int mi = 0; mi < 4; ++mi)
#pragma unroll
    for (int ni = 0; ni < 4; ++ni) {
      int row = m0 + wm + mi * 16 + quad * 4;
      int col = n0 + wn + ni * 16 + lr;
#pragma unroll
      for (int r = 0; r < 4; ++r) {
        float val = acc[mi][ni][r] * alpha;
        long long idx = cOff + (long long)(row + r) * p.cOsR + (long long)col * p.cOsC;
        if (p.outMode == 1) {
          p.C32[idx] = val;
        } else if (p.outMode == 0) {
          p.C16[idx] = (_Float16)val;
        } else if (p.outMode == 2) {
          _Float16 hi = (_Float16)val;
          p.C16[idx] = hi;
          p.C16lo[idx] = (_Float16)(val - (float)hi);
        } else {
          atomicAdd(&p.C32[idx], val);
        }
      }
    }
}

// ---------------------------------------------------------------- host
extern "C" void kernel_launch(void* const* d_in, const int* in_sizes, int n_in,
                              void* d_out, int out_size, void* d_ws, size_t ws_size,
                              hipStream_t stream) {
  const float* hidden = (const float*)d_in[0];   // (2,1024,2048)
  const float* memory = (const float*)d_in[1];   // (2048,1024)
  const float* Wq = (const float*)d_in[2];       // (1024,2048)
  const float* Wk = (const float*)d_in[3];       // (1024,1024)
  const float* Wv = (const float*)d_in[4];       // (1024,1024)
  const float* Wo = (const float*)d_in[5];       // (2048,1024)
  const float* log_beta = (const float*)d_in[6]; // (8,)
  const float* g_state = (const float*)d_in[7];
  const float* b_state = (const float*)d_in[8];
  const float* g_mem = (const float*)d_in[9];
  const float* b_mem = (const float*)d_in[10];

  char* w = (char*)d_ws;
  auto alloc = [&](size_t bytes) {
    char* r = w;
    w += (bytes + 255) & ~(size_t)255;
    return r;
  };
  _Float16* wq16 = (_Float16*)alloc(2097152 * 2);
  _Float16* wk16 = (_Float16*)alloc(1048576 * 2);
  _Float16* wv16 = (_Float16*)alloc(1048576 * 2);
  _Float16* wo16 = (_Float16*)alloc(2097152 * 2);
  _Float16* lnh16 = (_Float16*)alloc(4194304 * 2);
  _Float16* mn16 = (_Float16*)alloc(2097152 * 2);
  _Float16* kph = (_Float16*)alloc(2097152 * 2);   // K proj hi (n, h*128+d)
  _Float16* kpl = (_Float16*)alloc(2097152 * 2);   // K proj lo
  _Float16* vt16 = (_Float16*)alloc(2097152 * 2);  // V^T (h*128+d, n)
  _Float16* xih = (_Float16*)alloc(2097152 * 2);   // xi hi, layout (b*S+s, h*128+d)
  _Float16* xil = (_Float16*)alloc(2097152 * 2);   // xi lo
  float* xi32 = (float*)alloc(2097152 * 4);        // split-K fp32 accumulator
  float* crow = (float*)alloc(16384 * 4);
  float* scores = (float*)alloc((size_t)33554432 * 4);  // (b,h,s,n) fp32, 128 MB

  ln_rows<<<2048, 256, 0, stream>>>(hidden, g_state, b_state, lnh16, 2048);
  ln_rows<<<2048, 256, 0, stream>>>(memory, g_mem, b_mem, mn16, 1024);
  cast_f16<<<2048, 256, 0, stream>>>(Wq, wq16, 2097152);
  cast_f16<<<1024, 256, 0, stream>>>(Wk, wk16, 1048576);
  cast_f16<<<1024, 256, 0, stream>>>(Wv, wv16, 1048576);
  cast_f16<<<2048, 256, 0, stream>>>(Wo, wo16, 2097152);

  // Q = ln(hidden) @ Wq^T  -> xi (split store)
  {
    GemmParams p{};
    p.A = lnh16; p.lda = 2048;
    p.B = wq16; p.ldb = 2048;
    p.K = 2048;
    p.C16 = xih; p.C16lo = xil; p.outMode = 2;
    p.cOsR = 1024; p.cOsC = 1;
    gemm_nt<<<dim3(8, 16, 1), 256, 0, stream>>>(p);
  }
  // K proj (split store, row-major (n, hd))
  {
    GemmParams p{};
    p.A = mn16; p.lda = 1024;
    p.B = wk16; p.ldb = 1024;
    p.K = 1024;
    p.C16 = kph; p.C16lo = kpl; p.outMode = 2;
    p.cOsR = 1024; p.cOsC = 1;
    gemm_nt<<<dim3(8, 16, 1), 256, 0, stream>>>(p);
  }
  // V proj (plain, transposed store -> (hd, n))
  {
    GemmParams p{};
    p.A = mn16; p.lda = 1024;
    p.B = wv16; p.ldb = 1024;
    p.K = 1024;
    p.C16 = vt16; p.outMode = 0;
    p.cOsR = 1; p.cOsC = 2048;
    gemm_nt<<<dim3(8, 16, 1), 256, 0, stream>>>(p);
  }

  for (int step = 0; step < 3; ++step) {
    // scores = beta_h * xi @ K^T   (split inputs, fp32 out)
    {
      GemmParams p{};
      p.A = xih; p.Alo = xil; p.split = 1;
      p.lda = 1024; p.aSB = 1048576; p.aSH = 128;
      p.B = kph; p.Blo = kpl; p.ldb = 1024; p.bSH = 128;
      p.K = 128;
      p.alphaMode = 1; p.log_beta = log_beta;
      p.C32 = scores; p.outMode = 1;
      p.cSB = 16777216; p.cSH = 2097152;
      p.cOsR = 2048; p.cOsC = 1;
      gemm_nt<<<dim3(16, 8, 16), 256, 0, stream>>>(p);
    }
    entmax_crow<<<4096, 256, 0, stream>>>(scores, crow);
    zero_f32<<<2048, 256, 0, stream>>>(xi32, 2097152);
    // xi = entmax_w(scores) @ V   (fused w transform, split-K 8, fp32 atomic out)
    {
      GemmParams p{};
      p.aMode = 1;
      p.A32 = scores; p.crow = crow;
      p.lda = 2048; p.aSB = 16777216; p.aSH = 2097152;
      p.crowSB = 8192; p.crowSH = 1024;
      p.B = vt16; p.ldb = 2048; p.bSH = 262144;
      p.K = 2048; p.nsplit = 8;
      p.C32 = xi32; p.outMode = 3;
      p.cSB = 1048576; p.cSH = 128;
      p.cOsR = 1024; p.cOsC = 1;
      gemm_nt<<<dim3(8, 8, 16), 256, 0, stream>>>(p);
    }
    split_f16<<<2048, 256, 0, stream>>>(xi32, xih, xil, 2097152);
  }

  // out = xi @ Wo^T  (fp32 out)
  {
    GemmParams p{};
    p.A = xih; p.lda = 1024;
    p.B = wo16; p.ldb = 1024;
    p.K = 1024;
    p.C32 = (float*)d_out; p.outMode = 1;
    p.cOsR = 2048; p.cOsC = 1;
    gemm_nt<<<dim3(16, 16, 1), 256, 0, stream>>>(p);
  }
}

// Round 3
// 689.835 us; speedup vs baseline: 1.6016x; 1.4760x over previous
//
#include <hip/hip_runtime.h>

typedef _Float16 half8 __attribute__((ext_vector_type(8)));
typedef _Float16 hv4 __attribute__((ext_vector_type(4)));
typedef float fv4 __attribute__((ext_vector_type(4)));

typedef __attribute__((address_space(3))) unsigned lds_u32;
typedef const __attribute__((address_space(1))) unsigned glb_u32;

// async global->LDS, 16B per lane; dst is wave-uniform base, HW adds lane*16B
__device__ __forceinline__ void gll16(const void* g, void* l) {
  __builtin_amdgcn_global_load_lds((glb_u32*)g, (lds_u32*)l, 16, 0, 0);
}

// ---------------------------------------------------------------- LayerNorm
__global__ __launch_bounds__(256) void ln_rows(const float* __restrict__ in,
                                               const float* __restrict__ g,
                                               const float* __restrict__ bb,
                                               _Float16* __restrict__ out, int ncols) {
  __shared__ float sm[8];
  int row = blockIdx.x, t = threadIdx.x;
  const float* rp = in + (size_t)row * ncols;
  int nv = ncols >> 10;
  fv4 v[2];
  float s1 = 0.f, s2 = 0.f;
#pragma unroll
  for (int c = 0; c < 2; ++c)
    if (c < nv) {
      v[c] = *(const fv4*)(rp + c * 1024 + t * 4);
#pragma unroll
      for (int j = 0; j < 4; ++j) { s1 += v[c][j]; s2 += v[c][j] * v[c][j]; }
    }
#pragma unroll
  for (int off = 32; off > 0; off >>= 1) { s1 += __shfl_xor(s1, off, 64); s2 += __shfl_xor(s2, off, 64); }
  int w = t >> 6;
  if ((t & 63) == 0) { sm[w] = s1; sm[4 + w] = s2; }
  __syncthreads();
  s1 = sm[0] + sm[1] + sm[2] + sm[3];
  s2 = sm[4] + sm[5] + sm[6] + sm[7];
  float inv = 1.0f / (float)ncols;
  float mu = s1 * inv;
  float var = s2 * inv - mu * mu;
  float rstd = rsqrtf(var + 1e-5f);
#pragma unroll
  for (int c = 0; c < 2; ++c)
    if (c < nv) {
      int col = c * 1024 + t * 4;
      fv4 gg = *(const fv4*)(g + col);
      fv4 bv = *(const fv4*)(bb + col);
      hv4 o;
#pragma unroll
      for (int j = 0; j < 4; ++j) o[j] = (_Float16)(((v[c][j] - mu) * rstd) * gg[j] + bv[j]);
      *(hv4*)(out + (size_t)row * ncols + col) = o;
    }
}

// ---------------------------------------------------------------- fp32 -> fp16 cast
__global__ __launch_bounds__(256) void cast_f16(const float* __restrict__ in,
                                                _Float16* __restrict__ out, int n) {
  int i = (blockIdx.x * 256 + threadIdx.x) << 2;
  if (i < n) {
    fv4 f = *(const fv4*)(in + i);
    hv4 h;
#pragma unroll
    for (int j = 0; j < 4; ++j) h[j] = (_Float16)f[j];
    *(hv4*)(out + i) = h;
  }
}

// ---------------------------------------------------------------- sum ns partials -> hi/lo fp16
__global__ __launch_bounds__(256) void reduce_split(const float* __restrict__ parts, int ns,
                                                    long long stride, _Float16* __restrict__ hi,
                                                    _Float16* __restrict__ lo, int n) {
  int i = (blockIdx.x * 256 + threadIdx.x) << 2;
  if (i < n) {
    fv4 s = *(const fv4*)(parts + i);
    for (int j = 1; j < ns; ++j) {
      fv4 v = *(const fv4*)(parts + (size_t)j * stride + i);
      s += v;
    }
    hv4 h, l;
#pragma unroll
    for (int j = 0; j < 4; ++j) {
      h[j] = (_Float16)s[j];
      l[j] = (_Float16)(s[j] - (float)h[j]);
    }
    *(hv4*)(hi + i) = h;
    *(hv4*)(lo + i) = l;
  }
}

// ---------------------------------------------------------------- entmax-1.5: tau solve + w fp16
// One wave per score row (2048 fp32). Newton from tau=-1 + closed-form refinement on support.
// Writes w = (max(0,(s-m)/2 - tau))^2 as fp16 in-place (row-local: first half of the row's
// fp32 storage, stride 4096 halves).
__global__ __launch_bounds__(256) void entmax_w(const float* __restrict__ scores,
                                                _Float16* __restrict__ wout) {
  int row = blockIdx.x * 4 + (threadIdx.x >> 6);
  int l = threadIdx.x & 63;
  const fv4* sp = (const fv4*)(scores + (size_t)row * 2048);
  fv4 x[8];
#pragma unroll
  for (int i = 0; i < 8; ++i) x[i] = sp[i * 64 + l];
  float m = x[0][0];
#pragma unroll
  for (int i = 0; i < 8; ++i)
#pragma unroll
    for (int j = 0; j < 4; ++j) m = fmaxf(m, x[i][j]);
#pragma unroll
  for (int off = 32; off > 0; off >>= 1) m = fmaxf(m, __shfl_xor(m, off, 64));
#pragma unroll
  for (int i = 0; i < 8; ++i)
#pragma unroll
    for (int j = 0; j < 4; ++j) x[i][j] = (x[i][j] - m) * 0.5f;

  float tau = -1.0f;
  for (int it = 0; it < 12; ++it) {
    float f = 0.f, gs = 0.f;
#pragma unroll
    for (int i = 0; i < 8; ++i)
#pragma unroll
      for (int j = 0; j < 4; ++j) {
        float d = fmaxf(x[i][j] - tau, 0.f);
        f = fmaf(d, d, f);
        gs += d;
      }
#pragma unroll
    for (int off = 32; off > 0; off >>= 1) { f += __shfl_xor(f, off, 64); gs += __shfl_xor(gs, off, 64); }
    tau += (f - 1.0f) / (2.0f * gs);
    tau = fminf(fmaxf(tau, -1.0f), 0.0f);
  }
  float cnt = 0.f, s1 = 0.f, s2 = 0.f;
#pragma unroll
  for (int i = 0; i < 8; ++i)
#pragma unroll
    for (int j = 0; j < 4; ++j)
      if (x[i][j] > tau) { cnt += 1.f; s1 += x[i][j]; s2 = fmaf(x[i][j], x[i][j], s2); }
#pragma unroll
  for (int off = 32; off > 0; off >>= 1) {
    cnt += __shfl_xor(cnt, off, 64);
    s1 += __shfl_xor(s1, off, 64);
    s2 += __shfl_xor(s2, off, 64);
  }
  float mean = s1 / cnt;
  float ss = s2 - s1 * mean;
  float tstar = mean - sqrtf(fmaxf((1.0f - ss) / cnt, 0.0f));

  _Float16* wp = wout + (size_t)row * 4096;
#pragma unroll
  for (int i = 0; i < 8; ++i) {
    hv4 o;
#pragma unroll
    for (int j = 0; j < 4; ++j) {
      float d = fmaxf(x[i][j] - tstar, 0.f);
      o[j] = (_Float16)(d * d);
    }
    *(hv4*)(wp + (size_t)(i * 64 + l) * 4) = o;
  }
}

// ---------------------------------------------------------------- generic NT GEMM
// C[M,N] = alpha * A[M,K] @ B[N,K]^T.  128x128 tile, 4 waves, 4x4 16x16x32 f16 MFMA.
// SPLIT: A/B have hi+lo fp16 pairs, 3-pass MFMA (~fp32 accuracy).
// nsplit>1: blockIdx.x = ntile*nsplit + kchunk; partial fp32 out at C32 + ks*partStride.
// dual: blockIdx.z selects job {B,outMode} vs {B2,outModeB} (for fused K/V projection).
// outMode 0: fp16   1: fp32   2: fp16 hi+lo
struct GemmParams {
  const _Float16 *A, *Alo, *B, *Blo, *B2;
  _Float16 *C16, *C16lo, *C16b;
  float* C32;
  const float* log_beta;
  int K, lda, ldb;
  long long aSB, aSH, bSH;
  long long cSB, cSH, cOsR, cOsC;
  long long cOsRb, cOsCb;
  long long partStride;
  int alphaMode, outMode, outModeB, nsplit, dual;
};

template <int SPLIT>
__global__ __launch_bounds__(256) void gemm_nt(GemmParams p) {
  __shared__ __align__(16) _Float16 As[128 * 32];
  __shared__ __align__(16) _Float16 Bs[128 * 32];
  __shared__ __align__(16) _Float16 Asl[SPLIT ? 128 * 32 : 8];
  __shared__ __align__(16) _Float16 Bsl[SPLIT ? 128 * 32 : 8];
  int t = threadIdx.x;
  int m0 = blockIdx.y * 128;
  int bx = blockIdx.x, n0, kbeg, kend, ks = 0;
  if (p.nsplit > 1) {
    ks = bx % p.nsplit;
    n0 = (bx / p.nsplit) * 128;
    int kl = p.K / p.nsplit;
    kbeg = ks * kl;
    kend = kbeg + kl;
  } else {
    n0 = bx * 128;
    kbeg = 0;
    kend = p.K;
  }
  int z = blockIdx.z, bidx, h, job = 0;
  if (p.dual) { job = z; bidx = 0; h = 0; }
  else { bidx = z >> 3; h = z & 7; }
  const _Float16* pA = p.A + bidx * p.aSB + h * p.aSH;
  const _Float16* pAl = SPLIT ? p.Alo + bidx * p.aSB + h * p.aSH : nullptr;
  const _Float16* pB = (job ? p.B2 : p.B) + h * p.bSH;
  const _Float16* pBl = SPLIT ? p.Blo + h * p.bSH : nullptr;

  fv4 acc[4][4] = {};
  int wv = t >> 6, l = t & 63, quad = l >> 4, lr = l & 15;
  int wm = (wv >> 1) * 64, wn = (wv & 1) * 64;
  int rl = l >> 2, cl = (l & 3) * 8;  // lane row-in-16 / halves offset for staging

  for (int k0 = kbeg; k0 < kend; k0 += 32) {
#pragma unroll
    for (int v = 0; v < 2; ++v) {
      int rb = wv * 16 + v * 64;  // wave-uniform row base
      size_t aOff = (size_t)(m0 + rb + rl) * p.lda + k0 + cl;
      size_t bOff = (size_t)(n0 + rb + rl) * p.ldb + k0 + cl;
      gll16(pA + aOff, &As[rb * 32]);
      gll16(pB + bOff, &Bs[rb * 32]);
      if (SPLIT) {
        gll16(pAl + aOff, &Asl[rb * 32]);
        gll16(pBl + bOff, &Bsl[rb * 32]);
      }
    }
    __syncthreads();  // drains vmcnt(0): global_load_lds complete
    half8 ah[4], bh[4];
#pragma unroll
    for (int mi = 0; mi < 4; ++mi) ah[mi] = *(const half8*)&As[(wm + mi * 16 + lr) * 32 + quad * 8];
#pragma unroll
    for (int ni = 0; ni < 4; ++ni) bh[ni] = *(const half8*)&Bs[(wn + ni * 16 + lr) * 32 + quad * 8];
#pragma unroll
    for (int mi = 0; mi < 4; ++mi)
#pragma unroll
      for (int ni = 0; ni < 4; ++ni)
        acc[mi][ni] = __builtin_amdgcn_mfma_f32_16x16x32_f16(ah[mi], bh[ni], acc[mi][ni], 0, 0, 0);
    if (SPLIT) {
      half8 al[4], bl[4];
#pragma unroll
      for (int mi = 0; mi < 4; ++mi) al[mi] = *(const half8*)&Asl[(wm + mi * 16 + lr) * 32 + quad * 8];
#pragma unroll
      for (int ni = 0; ni < 4; ++ni) bl[ni] = *(const half8*)&Bsl[(wn + ni * 16 + lr) * 32 + quad * 8];
#pragma unroll
      for (int mi = 0; mi < 4; ++mi)
#pragma unroll
        for (int ni = 0; ni < 4; ++ni) {
          acc[mi][ni] = __builtin_amdgcn_mfma_f32_16x16x32_f16(al[mi], bh[ni], acc[mi][ni], 0, 0, 0);
          acc[mi][ni] = __builtin_amdgcn_mfma_f32_16x16x32_f16(ah[mi], bl[ni], acc[mi][ni], 0, 0, 0);
        }
    }
    __syncthreads();
  }

  float alpha = p.alphaMode ? __expf(p.log_beta[h]) : 1.0f;
  int om = (p.dual && job) ? p.outModeB : p.outMode;
  _Float16* c16 = (p.dual && job) ? p.C16b : p.C16;
  long long osR = (p.dual && job) ? p.cOsRb : p.cOsR;
  long long osC = (p.dual && job) ? p.cOsCb : p.cOsC;
  float* c32 = p.C32 + (p.nsplit > 1 ? (long long)ks * p.partStride : 0);
  long long cOff = (long long)bidx * p.cSB + (long long)h * p.cSH;
#pragma unroll
  for (int mi = 0; mi < 4; ++mi)
#pragma unroll
    for (int ni = 0; ni < 4; ++ni) {
      int row = m0 + wm + mi * 16 + quad * 4;
      int col = n0 + wn + ni * 16 + lr;
#pragma unroll
      for (int r = 0; r < 4; ++r) {
        float val = acc[mi][ni][r] * alpha;
        long long idx = cOff + (long long)(row + r) * osR + (long long)col * osC;
        if (om == 1) {
          c32[idx] = val;
        } else if (om == 0) {
          c16[idx] = (_Float16)val;
        } else {
          _Float16 hi = (_Float16)val;
          c16[idx] = hi;
          p.C16lo[idx] = (_Float16)(val - (float)hi);
        }
      }
    }
}

// ---------------------------------------------------------------- host
extern "C" void kernel_launch(void* const* d_in, const int* in_sizes, int n_in,
                              void* d_out, int out_size, void* d_ws, size_t ws_size,
                              hipStream_t stream) {
  const float* hidden = (const float*)d_in[0];   // (2,1024,2048)
  const float* memory = (const float*)d_in[1];   // (2048,1024)
  const float* Wq = (const float*)d_in[2];       // (1024,2048)
  const float* Wk = (const float*)d_in[3];       // (1024,1024)
  const float* Wv = (const float*)d_in[4];       // (1024,1024)
  const float* Wo = (const float*)d_in[5];       // (2048,1024)
  const float* log_beta = (const float*)d_in[6]; // (8,)
  const float* g_state = (const float*)d_in[7];
  const float* b_state = (const float*)d_in[8];
  const float* g_mem = (const float*)d_in[9];
  const float* b_mem = (const float*)d_in[10];

  char* w = (char*)d_ws;
  auto alloc = [&](size_t bytes) {
    char* r = w;
    w += (bytes + 255) & ~(size_t)255;
    return r;
  };
  _Float16* wq16 = (_Float16*)alloc(2097152 * 2);
  _Float16* wk16 = (_Float16*)alloc(1048576 * 2);
  _Float16* wv16 = (_Float16*)alloc(1048576 * 2);
  _Float16* wo16 = (_Float16*)alloc(2097152 * 2);
  _Float16* lnh16 = (_Float16*)alloc(4194304 * 2);
  _Float16* mn16 = (_Float16*)alloc(2097152 * 2);
  _Float16* kph = (_Float16*)alloc(2097152 * 2);   // K proj hi (n, h*128+d)
  _Float16* kpl = (_Float16*)alloc(2097152 * 2);   // K proj lo
  _Float16* vt16 = (_Float16*)alloc(2097152 * 2);  // V^T (h*128+d, n)
  _Float16* xih = (_Float16*)alloc(2097152 * 2);   // xi hi (b*S+s, h*128+d)
  _Float16* xil = (_Float16*)alloc(2097152 * 2);   // xi lo
  float* parts = (float*)alloc((size_t)8 * 2097152 * 4);  // split-K partials, 64 MB
  float* scores = (float*)alloc((size_t)33554432 * 4);    // (b,h,s,n) fp32; w fp16 in-place

  ln_rows<<<2048, 256, 0, stream>>>(hidden, g_state, b_state, lnh16, 2048);
  ln_rows<<<2048, 256, 0, stream>>>(memory, g_mem, b_mem, mn16, 1024);
  cast_f16<<<2048, 256, 0, stream>>>(Wq, wq16, 2097152);
  cast_f16<<<1024, 256, 0, stream>>>(Wk, wk16, 1048576);
  cast_f16<<<1024, 256, 0, stream>>>(Wv, wv16, 1048576);
  cast_f16<<<2048, 256, 0, stream>>>(Wo, wo16, 2097152);

  // Q = ln(hidden) @ Wq^T  (split-K=2 partials -> reduce -> xi hi/lo)
  {
    GemmParams p{};
    p.A = lnh16; p.lda = 2048;
    p.B = wq16; p.ldb = 2048;
    p.K = 2048; p.nsplit = 2;
    p.C32 = parts; p.outMode = 1; p.partStride = 2097152;
    p.cOsR = 1024; p.cOsC = 1;
    gemm_nt<0><<<dim3(16, 16, 1), 256, 0, stream>>>(p);
    reduce_split<<<2048, 256, 0, stream>>>(parts, 2, 2097152, xih, xil, 2097152);
  }
  // K & V projections in one dual-job launch
  {
    GemmParams p{};
    p.A = mn16; p.lda = 1024;
    p.B = wk16; p.B2 = wv16; p.ldb = 1024;
    p.K = 1024; p.dual = 1;
    p.C16 = kph; p.C16lo = kpl; p.outMode = 2; p.cOsR = 1024; p.cOsC = 1;
    p.C16b = vt16; p.outModeB = 0; p.cOsRb = 1; p.cOsCb = 2048;
    gemm_nt<0><<<dim3(8, 16, 2), 256, 0, stream>>>(p);
  }

  for (int step = 0; step < 3; ++step) {
    // scores = beta_h * xi @ K^T  (hi/lo 3-pass, fp32 out)
    {
      GemmParams p{};
      p.A = xih; p.Alo = xil;
      p.lda = 1024; p.aSB = 1048576; p.aSH = 128;
      p.B = kph; p.Blo = kpl; p.ldb = 1024; p.bSH = 128;
      p.K = 128;
      p.alphaMode = 1; p.log_beta = log_beta;
      p.C32 = scores; p.outMode = 1;
      p.cSB = 16777216; p.cSH = 2097152;
      p.cOsR = 2048; p.cOsC = 1;
      gemm_nt<1><<<dim3(16, 8, 16), 256, 0, stream>>>(p);
    }
    entmax_w<<<4096, 256, 0, stream>>>(scores, (_Float16*)scores);
    // xi = w @ V  (plain fp16, split-K=8 partials -> reduce -> xi hi/lo)
    {
      GemmParams p{};
      p.A = (const _Float16*)scores;  // w fp16, stride 4096 halves
      p.lda = 4096; p.aSB = 33554432; p.aSH = 4194304;
      p.B = vt16; p.ldb = 2048; p.bSH = 262144;
      p.K = 2048; p.nsplit = 8;
      p.C32 = parts; p.outMode = 1; p.partStride = 2097152;
      p.cSB = 1048576; p.cSH = 128;
      p.cOsR = 1024; p.cOsC = 1;
      gemm_nt<0><<<dim3(8, 8, 16), 256, 0, stream>>>(p);
    }
    reduce_split<<<2048, 256, 0, stream>>>(parts, 8, 2097152, xih, xil, 2097152);
  }

  // out = xi @ Wo^T  (fp32 out)
  {
    GemmParams p{};
    p.A = xih; p.lda = 1024;
    p.B = wo16; p.ldb = 1024;
    p.K = 1024;
    p.C32 = (float*)d_out; p.outMode = 1;
    p.cOsR = 2048; p.cOsC = 1;
    gemm_nt<0><<<dim3(16, 16, 1), 256, 0, stream>>>(p);
  }
}

// Round 4
// 640.657 us; speedup vs baseline: 1.7245x; 1.0768x over previous
//
#include <hip/hip_runtime.h>

typedef _Float16 half8 __attribute__((ext_vector_type(8)));
typedef _Float16 hv4 __attribute__((ext_vector_type(4)));
typedef float fv4 __attribute__((ext_vector_type(4)));

typedef __attribute__((address_space(3))) unsigned lds_u32;
typedef const __attribute__((address_space(1))) unsigned glb_u32;

// async global->LDS, 16B per lane; dst is wave-uniform base, HW adds lane*16B
__device__ __forceinline__ void gll16(const void* g, void* l) {
  __builtin_amdgcn_global_load_lds((glb_u32*)g, (lds_u32*)l, 16, 0, 0);
}

// ---------------------------------------------------------------- LayerNorm
__global__ __launch_bounds__(256) void ln_rows(const float* __restrict__ in,
                                               const float* __restrict__ g,
                                               const float* __restrict__ bb,
                                               _Float16* __restrict__ out, int ncols) {
  __shared__ float sm[8];
  int row = blockIdx.x, t = threadIdx.x;
  const float* rp = in + (size_t)row * ncols;
  int nv = ncols >> 10;
  fv4 v[2];
  float s1 = 0.f, s2 = 0.f;
#pragma unroll
  for (int c = 0; c < 2; ++c)
    if (c < nv) {
      v[c] = *(const fv4*)(rp + c * 1024 + t * 4);
#pragma unroll
      for (int j = 0; j < 4; ++j) { s1 += v[c][j]; s2 += v[c][j] * v[c][j]; }
    }
#pragma unroll
  for (int off = 32; off > 0; off >>= 1) { s1 += __shfl_xor(s1, off, 64); s2 += __shfl_xor(s2, off, 64); }
  int w = t >> 6;
  if ((t & 63) == 0) { sm[w] = s1; sm[4 + w] = s2; }
  __syncthreads();
  s1 = sm[0] + sm[1] + sm[2] + sm[3];
  s2 = sm[4] + sm[5] + sm[6] + sm[7];
  float inv = 1.0f / (float)ncols;
  float mu = s1 * inv;
  float var = s2 * inv - mu * mu;
  float rstd = rsqrtf(var + 1e-5f);
#pragma unroll
  for (int c = 0; c < 2; ++c)
    if (c < nv) {
      int col = c * 1024 + t * 4;
      fv4 gg = *(const fv4*)(g + col);
      fv4 bv = *(const fv4*)(bb + col);
      hv4 o;
#pragma unroll
      for (int j = 0; j < 4; ++j) o[j] = (_Float16)(((v[c][j] - mu) * rstd) * gg[j] + bv[j]);
      *(hv4*)(out + (size_t)row * ncols + col) = o;
    }
}

// ---------------------------------------------------------------- fp32 -> fp16 cast
__global__ __launch_bounds__(256) void cast_f16(const float* __restrict__ in,
                                                _Float16* __restrict__ out, int n) {
  int i = (blockIdx.x * 256 + threadIdx.x) << 2;
  if (i < n) {
    fv4 f = *(const fv4*)(in + i);
    hv4 h;
#pragma unroll
    for (int j = 0; j < 4; ++j) h[j] = (_Float16)f[j];
    *(hv4*)(out + i) = h;
  }
}

// ---------------------------------------------------------------- sum ns partials -> hi/lo fp16
__global__ __launch_bounds__(256) void reduce_split(const float* __restrict__ parts, int ns,
                                                    long long stride, _Float16* __restrict__ hi,
                                                    _Float16* __restrict__ lo, int n) {
  int i = (blockIdx.x * 256 + threadIdx.x) << 2;
  if (i < n) {
    fv4 s = *(const fv4*)(parts + i);
    for (int j = 1; j < ns; ++j) {
      fv4 v = *(const fv4*)(parts + (size_t)j * stride + i);
      s += v;
    }
    hv4 h, l;
#pragma unroll
    for (int j = 0; j < 4; ++j) {
      h[j] = (_Float16)s[j];
      l[j] = (_Float16)(s[j] - (float)h[j]);
    }
    *(hv4*)(hi + i) = h;
    *(hv4*)(lo + i) = l;
  }
}

// ---------------------------------------------------------------- entmax-1.5: tau + w fp16
// One wave per score row (2048 fp32). Michelot-style exact support iteration:
// S0 = all; tau_S = mean_S - sqrt((1 - ss_S)/|S|); S <- {x > tau_S}; repeat to fixpoint
// (exact: at the fixpoint sum (x-tau)+^2 = 1, same as reference). Early-exit, max 10.
// Writes w = (max(0,(s-m)/2 - tau))^2 as fp16 in-place (row-local, stride 4096 halves).
__global__ __launch_bounds__(256) void entmax_w(const float* __restrict__ scores,
                                                _Float16* __restrict__ wout) {
  int row = blockIdx.x * 4 + (threadIdx.x >> 6);
  int l = threadIdx.x & 63;
  const fv4* sp = (const fv4*)(scores + (size_t)row * 2048);
  fv4 x[8];
#pragma unroll
  for (int i = 0; i < 8; ++i) x[i] = sp[i * 64 + l];
  float m = x[0][0];
#pragma unroll
  for (int i = 0; i < 8; ++i)
#pragma unroll
    for (int j = 0; j < 4; ++j) m = fmaxf(m, x[i][j]);
#pragma unroll
  for (int off = 32; off > 0; off >>= 1) m = fmaxf(m, __shfl_xor(m, off, 64));
#pragma unroll
  for (int i = 0; i < 8; ++i)
#pragma unroll
    for (int j = 0; j < 4; ++j) x[i][j] = (x[i][j] - m) * 0.5f;

  float tau = -1e30f;
  for (int it = 0; it < 10; ++it) {
    float cnt = 0.f, s1 = 0.f, s2 = 0.f;
#pragma unroll
    for (int i = 0; i < 8; ++i)
#pragma unroll
      for (int j = 0; j < 4; ++j)
        if (x[i][j] > tau) { cnt += 1.f; s1 += x[i][j]; s2 = fmaf(x[i][j], x[i][j], s2); }
#pragma unroll
    for (int off = 32; off > 0; off >>= 1) {
      cnt += __shfl_xor(cnt, off, 64);
      s1 += __shfl_xor(s1, off, 64);
      s2 += __shfl_xor(s2, off, 64);
    }
    float mean = s1 / cnt;
    float ss = s2 - s1 * mean;  // = sum_S (x - mean)^2
    float nt = mean - sqrtf(fmaxf((1.0f - ss) / cnt, 0.0f));
    if (nt == tau) break;  // wave-uniform (butterfly reduce gives all lanes the sums)
    tau = nt;
  }

  _Float16* wp = wout + (size_t)row * 4096;
#pragma unroll
  for (int i = 0; i < 8; ++i) {
    hv4 o;
#pragma unroll
    for (int j = 0; j < 4; ++j) {
      float d = fmaxf(x[i][j] - tau, 0.f);
      o[j] = (_Float16)(d * d);
    }
    *(hv4*)(wp + (size_t)(i * 64 + l) * 4) = o;
  }
}

// ---------------------------------------------------------------- generic NT GEMM
// C[M,N] = alpha * A[M,K] @ B[N,K]^T.  128x128 tile, 4 waves, 4x4 16x16x32 f16 MFMA.
// SPLIT: A/B have hi+lo fp16 pairs, 3-pass MFMA (~fp32 accuracy).
// nsplit>1: blockIdx.x = ntile*nsplit + kchunk; partial fp32 out at C32 + ks*partStride.
// dual: blockIdx.z selects job {B,outMode} vs {B2,outModeB} (for fused K/V projection).
// outMode 0: fp16   1: fp32   2: fp16 hi+lo
struct GemmParams {
  const _Float16 *A, *Alo, *B, *Blo, *B2;
  _Float16 *C16, *C16lo, *C16b;
  float* C32;
  const float* log_beta;
  int K, lda, ldb;
  long long aSB, aSH, bSH;
  long long cSB, cSH, cOsR, cOsC;
  long long cOsRb, cOsCb;
  long long partStride;
  int alphaMode, outMode, outModeB, nsplit, dual;
};

template <int SPLIT>
__global__ __launch_bounds__(256) void gemm_nt(GemmParams p) {
  __shared__ __align__(16) _Float16 As[128 * 32];
  __shared__ __align__(16) _Float16 Bs[128 * 32];
  __shared__ __align__(16) _Float16 Asl[SPLIT ? 128 * 32 : 8];
  __shared__ __align__(16) _Float16 Bsl[SPLIT ? 128 * 32 : 8];
  int t = threadIdx.x;
  int m0 = blockIdx.y * 128;
  int bx = blockIdx.x, n0, kbeg, kend, ks = 0;
  if (p.nsplit > 1) {
    ks = bx % p.nsplit;
    n0 = (bx / p.nsplit) * 128;
    int kl = p.K / p.nsplit;
    kbeg = ks * kl;
    kend = kbeg + kl;
  } else {
    n0 = bx * 128;
    kbeg = 0;
    kend = p.K;
  }
  int z = blockIdx.z, bidx, h, job = 0;
  if (p.dual) { job = z; bidx = 0; h = 0; }
  else { bidx = z >> 3; h = z & 7; }
  const _Float16* pA = p.A + bidx * p.aSB + h * p.aSH;
  const _Float16* pAl = SPLIT ? p.Alo + bidx * p.aSB + h * p.aSH : nullptr;
  const _Float16* pB = (job ? p.B2 : p.B) + h * p.bSH;
  const _Float16* pBl = SPLIT ? p.Blo + h * p.bSH : nullptr;

  fv4 acc[4][4] = {};
  int wv = t >> 6, l = t & 63, quad = l >> 4, lr = l & 15;
  int wm = (wv >> 1) * 64, wn = (wv & 1) * 64;
  int rl = l >> 2, cl = (l & 3) * 8;  // lane row-in-16 / halves offset for staging

  for (int k0 = kbeg; k0 < kend; k0 += 32) {
#pragma unroll
    for (int v = 0; v < 2; ++v) {
      int rb = wv * 16 + v * 64;  // wave-uniform row base
      size_t aOff = (size_t)(m0 + rb + rl) * p.lda + k0 + cl;
      size_t bOff = (size_t)(n0 + rb + rl) * p.ldb + k0 + cl;
      gll16(pA + aOff, &As[rb * 32]);
      gll16(pB + bOff, &Bs[rb * 32]);
      if (SPLIT) {
        gll16(pAl + aOff, &Asl[rb * 32]);
        gll16(pBl + bOff, &Bsl[rb * 32]);
      }
    }
    __syncthreads();  // drains vmcnt(0): global_load_lds complete
    half8 ah[4], bh[4];
#pragma unroll
    for (int mi = 0; mi < 4; ++mi) ah[mi] = *(const half8*)&As[(wm + mi * 16 + lr) * 32 + quad * 8];
#pragma unroll
    for (int ni = 0; ni < 4; ++ni) bh[ni] = *(const half8*)&Bs[(wn + ni * 16 + lr) * 32 + quad * 8];
#pragma unroll
    for (int mi = 0; mi < 4; ++mi)
#pragma unroll
      for (int ni = 0; ni < 4; ++ni)
        acc[mi][ni] = __builtin_amdgcn_mfma_f32_16x16x32_f16(ah[mi], bh[ni], acc[mi][ni], 0, 0, 0);
    if (SPLIT) {
      half8 al[4], bl[4];
#pragma unroll
      for (int mi = 0; mi < 4; ++mi) al[mi] = *(const half8*)&Asl[(wm + mi * 16 + lr) * 32 + quad * 8];
#pragma unroll
      for (int ni = 0; ni < 4; ++ni) bl[ni] = *(const half8*)&Bsl[(wn + ni * 16 + lr) * 32 + quad * 8];
#pragma unroll
      for (int mi = 0; mi < 4; ++mi)
#pragma unroll
        for (int ni = 0; ni < 4; ++ni) {
          acc[mi][ni] = __builtin_amdgcn_mfma_f32_16x16x32_f16(al[mi], bh[ni], acc[mi][ni], 0, 0, 0);
          acc[mi][ni] = __builtin_amdgcn_mfma_f32_16x16x32_f16(ah[mi], bl[ni], acc[mi][ni], 0, 0, 0);
        }
    }
    __syncthreads();
  }

  float alpha = p.alphaMode ? __expf(p.log_beta[h]) : 1.0f;
  int om = (p.dual && job) ? p.outModeB : p.outMode;
  _Float16* c16 = (p.dual && job) ? p.C16b : p.C16;
  long long osR = (p.dual && job) ? p.cOsRb : p.cOsR;
  long long osC = (p.dual && job) ? p.cOsCb : p.cOsC;
  float* c32 = p.C32 + (p.nsplit > 1 ? (long long)ks * p.partStride : 0);
  long long cOff = (long long)bidx * p.cSB + (long long)h * p.cSH;
#pragma unroll
  for (int mi = 0; mi < 4; ++mi)
#pragma unroll
    for (int ni = 0; ni < 4; ++ni) {
      int row = m0 + wm + mi * 16 + quad * 4;
      int col = n0 + wn + ni * 16 + lr;
#pragma unroll
      for (int r = 0; r < 4; ++r) {
        float val = acc[mi][ni][r] * alpha;
        long long idx = cOff + (long long)(row + r) * osR + (long long)col * osC;
        if (om == 1) {
          c32[idx] = val;
        } else if (om == 0) {
          c16[idx] = (_Float16)val;
        } else {
          _Float16 hi = (_Float16)val;
          c16[idx] = hi;
          p.C16lo[idx] = (_Float16)(val - (float)hi);
        }
      }
    }
}

// ---------------------------------------------------------------- host
extern "C" void kernel_launch(void* const* d_in, const int* in_sizes, int n_in,
                              void* d_out, int out_size, void* d_ws, size_t ws_size,
                              hipStream_t stream) {
  const float* hidden = (const float*)d_in[0];   // (2,1024,2048)
  const float* memory = (const float*)d_in[1];   // (2048,1024)
  const float* Wq = (const float*)d_in[2];       // (1024,2048)
  const float* Wk = (const float*)d_in[3];       // (1024,1024)
  const float* Wv = (const float*)d_in[4];       // (1024,1024)
  const float* Wo = (const float*)d_in[5];       // (2048,1024)
  const float* log_beta = (const float*)d_in[6]; // (8,)
  const float* g_state = (const float*)d_in[7];
  const float* b_state = (const float*)d_in[8];
  const float* g_mem = (const float*)d_in[9];
  const float* b_mem = (const float*)d_in[10];

  char* w = (char*)d_ws;
  auto alloc = [&](size_t bytes) {
    char* r = w;
    w += (bytes + 255) & ~(size_t)255;
    return r;
  };
  _Float16* wq16 = (_Float16*)alloc(2097152 * 2);
  _Float16* wk16 = (_Float16*)alloc(1048576 * 2);
  _Float16* wv16 = (_Float16*)alloc(1048576 * 2);
  _Float16* wo16 = (_Float16*)alloc(2097152 * 2);
  _Float16* lnh16 = (_Float16*)alloc(4194304 * 2);
  _Float16* mn16 = (_Float16*)alloc(2097152 * 2);
  _Float16* kph = (_Float16*)alloc(2097152 * 2);   // K proj hi (n, h*128+d)
  _Float16* kpl = (_Float16*)alloc(2097152 * 2);   // K proj lo
  _Float16* vt16 = (_Float16*)alloc(2097152 * 2);  // V^T (h*128+d, n)
  _Float16* xih = (_Float16*)alloc(2097152 * 2);   // xi hi (b*S+s, h*128+d)
  _Float16* xil = (_Float16*)alloc(2097152 * 2);   // xi lo
  float* parts = (float*)alloc((size_t)8 * 2097152 * 4);  // split-K partials
  float* scores = (float*)alloc((size_t)33554432 * 4);    // (b,h,s,n) fp32; w fp16 in-place

  ln_rows<<<2048, 256, 0, stream>>>(hidden, g_state, b_state, lnh16, 2048);
  ln_rows<<<2048, 256, 0, stream>>>(memory, g_mem, b_mem, mn16, 1024);
  cast_f16<<<2048, 256, 0, stream>>>(Wq, wq16, 2097152);
  cast_f16<<<1024, 256, 0, stream>>>(Wk, wk16, 1048576);
  cast_f16<<<1024, 256, 0, stream>>>(Wv, wv16, 1048576);
  cast_f16<<<2048, 256, 0, stream>>>(Wo, wo16, 2097152);

  // Q = ln(hidden) @ Wq^T  (split-K=2 partials -> reduce -> xi hi/lo)
  {
    GemmParams p{};
    p.A = lnh16; p.lda = 2048;
    p.B = wq16; p.ldb = 2048;
    p.K = 2048; p.nsplit = 2;
    p.C32 = parts; p.outMode = 1; p.partStride = 2097152;
    p.cOsR = 1024; p.cOsC = 1;
    gemm_nt<0><<<dim3(16, 16, 1), 256, 0, stream>>>(p);
    reduce_split<<<2048, 256, 0, stream>>>(parts, 2, 2097152, xih, xil, 2097152);
  }
  // K & V projections in one dual-job launch
  {
    GemmParams p{};
    p.A = mn16; p.lda = 1024;
    p.B = wk16; p.B2 = wv16; p.ldb = 1024;
    p.K = 1024; p.dual = 1;
    p.C16 = kph; p.C16lo = kpl; p.outMode = 2; p.cOsR = 1024; p.cOsC = 1;
    p.C16b = vt16; p.outModeB = 0; p.cOsRb = 1; p.cOsCb = 2048;
    gemm_nt<0><<<dim3(8, 16, 2), 256, 0, stream>>>(p);
  }

  for (int step = 0; step < 3; ++step) {
    // scores = beta_h * xi @ K^T  (hi/lo 3-pass, fp32 out)
    {
      GemmParams p{};
      p.A = xih; p.Alo = xil;
      p.lda = 1024; p.aSB = 1048576; p.aSH = 128;
      p.B = kph; p.Blo = kpl; p.ldb = 1024; p.bSH = 128;
      p.K = 128;
      p.alphaMode = 1; p.log_beta = log_beta;
      p.C32 = scores; p.outMode = 1;
      p.cSB = 16777216; p.cSH = 2097152;
      p.cOsR = 2048; p.cOsC = 1;
      gemm_nt<1><<<dim3(16, 8, 16), 256, 0, stream>>>(p);
    }
    entmax_w<<<4096, 256, 0, stream>>>(scores, (_Float16*)scores);
    // xi = w @ V  (plain fp16, split-K=2 partials -> reduce -> xi hi/lo)
    {
      GemmParams p{};
      p.A = (const _Float16*)scores;  // w fp16, stride 4096 halves
      p.lda = 4096; p.aSB = 33554432; p.aSH = 4194304;
      p.B = vt16; p.ldb = 2048; p.bSH = 262144;
      p.K = 2048; p.nsplit = 2;
      p.C32 = parts; p.outMode = 1; p.partStride = 2097152;
      p.cSB = 1048576; p.cSH = 128;
      p.cOsR = 1024; p.cOsC = 1;
      gemm_nt<0><<<dim3(2, 8, 16), 256, 0, stream>>>(p);
    }
    reduce_split<<<2048, 256, 0, stream>>>(parts, 2, 2097152, xih, xil, 2097152);
  }

  // out = xi @ Wo^T  (fp32 out)
  {
    GemmParams p{};
    p.A = xih; p.lda = 1024;
    p.B = wo16; p.ldb = 1024;
    p.K = 1024;
    p.C32 = (float*)d_out; p.outMode = 1;
    p.cOsR = 2048; p.cOsC = 1;
    gemm_nt<0><<<dim3(16, 16, 1), 256, 0, stream>>>(p);
  }
}

// Round 5
// 617.734 us; speedup vs baseline: 1.7885x; 1.0371x over previous
//
#include <hip/hip_runtime.h>

typedef _Float16 half8 __attribute__((ext_vector_type(8)));
typedef _Float16 hv4 __attribute__((ext_vector_type(4)));
typedef float fv4 __attribute__((ext_vector_type(4)));

typedef __attribute__((address_space(3))) unsigned lds_u32;
typedef const __attribute__((address_space(1))) unsigned glb_u32;

// async global->LDS, 16B per lane; dst is wave-uniform base, HW adds lane*16B
__device__ __forceinline__ void gll16(const void* g, void* l) {
  __builtin_amdgcn_global_load_lds((glb_u32*)g, (lds_u32*)l, 16, 0, 0);
}

// ---------------------------------------------------------------- LayerNorm
__global__ __launch_bounds__(256) void ln_rows(const float* __restrict__ in,
                                               const float* __restrict__ g,
                                               const float* __restrict__ bb,
                                               _Float16* __restrict__ out, int ncols) {
  __shared__ float sm[8];
  int row = blockIdx.x, t = threadIdx.x;
  const float* rp = in + (size_t)row * ncols;
  int nv = ncols >> 10;
  fv4 v[2];
  float s1 = 0.f, s2 = 0.f;
#pragma unroll
  for (int c = 0; c < 2; ++c)
    if (c < nv) {
      v[c] = *(const fv4*)(rp + c * 1024 + t * 4);
#pragma unroll
      for (int j = 0; j < 4; ++j) { s1 += v[c][j]; s2 += v[c][j] * v[c][j]; }
    }
#pragma unroll
  for (int off = 32; off > 0; off >>= 1) { s1 += __shfl_xor(s1, off, 64); s2 += __shfl_xor(s2, off, 64); }
  int w = t >> 6;
  if ((t & 63) == 0) { sm[w] = s1; sm[4 + w] = s2; }
  __syncthreads();
  s1 = sm[0] + sm[1] + sm[2] + sm[3];
  s2 = sm[4] + sm[5] + sm[6] + sm[7];
  float inv = 1.0f / (float)ncols;
  float mu = s1 * inv;
  float var = s2 * inv - mu * mu;
  float rstd = rsqrtf(var + 1e-5f);
#pragma unroll
  for (int c = 0; c < 2; ++c)
    if (c < nv) {
      int col = c * 1024 + t * 4;
      fv4 gg = *(const fv4*)(g + col);
      fv4 bv = *(const fv4*)(bb + col);
      hv4 o;
#pragma unroll
      for (int j = 0; j < 4; ++j) o[j] = (_Float16)(((v[c][j] - mu) * rstd) * gg[j] + bv[j]);
      *(hv4*)(out + (size_t)row * ncols + col) = o;
    }
}

// ---------------------------------------------------------------- fp32 -> fp16 cast
__global__ __launch_bounds__(256) void cast_f16(const float* __restrict__ in,
                                                _Float16* __restrict__ out, int n) {
  int i = (blockIdx.x * 256 + threadIdx.x) << 2;
  if (i < n) {
    fv4 f = *(const fv4*)(in + i);
    hv4 h;
#pragma unroll
    for (int j = 0; j < 4; ++j) h[j] = (_Float16)f[j];
    *(hv4*)(out + i) = h;
  }
}

// ---------------------------------------------------------------- sum ns partials -> hi/lo fp16
__global__ __launch_bounds__(256) void reduce_split(const float* __restrict__ parts, int ns,
                                                    long long stride, _Float16* __restrict__ hi,
                                                    _Float16* __restrict__ lo, int n) {
  int i = (blockIdx.x * 256 + threadIdx.x) << 2;
  if (i < n) {
    fv4 s = *(const fv4*)(parts + i);
    for (int j = 1; j < ns; ++j) {
      fv4 v = *(const fv4*)(parts + (size_t)j * stride + i);
      s += v;
    }
    hv4 h, l;
#pragma unroll
    for (int j = 0; j < 4; ++j) {
      h[j] = (_Float16)s[j];
      l[j] = (_Float16)(s[j] - (float)h[j]);
    }
    *(hv4*)(hi + i) = h;
    *(hv4*)(lo + i) = l;
  }
}

// ---------------------------------------------------------------- entmax-1.5: tau + w fp16
// One wave per score row (2048 fp32). Michelot exact support iteration, starting from the
// valid superset S0 = {x > -1} (tau* >= -1 always). cnt comes from ballot+popcount (SALU,
// no cross-lane float reduce); x^2 hoisted. Fixpoint tau is exact (same as reference sort).
// Writes w = (max(0,(s-m)/2 - tau))^2 as fp16 in-place (row-local, stride 4096 halves).
__global__ __launch_bounds__(256) void entmax_w(const float* __restrict__ scores,
                                                _Float16* __restrict__ wout) {
  int row = blockIdx.x * 4 + (threadIdx.x >> 6);
  int l = threadIdx.x & 63;
  const fv4* sp = (const fv4*)(scores + (size_t)row * 2048);
  fv4 x[8];
#pragma unroll
  for (int i = 0; i < 8; ++i) x[i] = sp[i * 64 + l];
  float m = x[0][0];
#pragma unroll
  for (int i = 0; i < 8; ++i)
#pragma unroll
    for (int j = 0; j < 4; ++j) m = fmaxf(m, x[i][j]);
#pragma unroll
  for (int off = 32; off > 0; off >>= 1) m = fmaxf(m, __shfl_xor(m, off, 64));
  fv4 xx[8];
#pragma unroll
  for (int i = 0; i < 8; ++i)
#pragma unroll
    for (int j = 0; j < 4; ++j) {
      x[i][j] = (x[i][j] - m) * 0.5f;
      xx[i][j] = x[i][j] * x[i][j];
    }

  float tau = -1.0f;  // tau* in [-1, 0]; S0 = {x > -1} is a superset of the support
  for (int it = 0; it < 12; ++it) {
    float s1 = 0.f, s2 = 0.f;
    int cnti = 0;
#pragma unroll
    for (int i = 0; i < 8; ++i)
#pragma unroll
      for (int j = 0; j < 4; ++j) {
        bool a = x[i][j] > tau;
        cnti += (int)__builtin_popcountll(__ballot(a));  // SALU: s_bcnt1 + s_add
        s1 += a ? x[i][j] : 0.f;
        s2 += a ? xx[i][j] : 0.f;
      }
#pragma unroll
    for (int off = 32; off > 0; off >>= 1) {
      s1 += __shfl_xor(s1, off, 64);
      s2 += __shfl_xor(s2, off, 64);
    }
    float cnt = (float)cnti;
    float mean = s1 / cnt;
    float ss = s2 - s1 * mean;  // = sum_S (x - mean)^2
    float nt = mean - sqrtf(fmaxf((1.0f - ss) / cnt, 0.0f));
    if (nt == tau) break;  // wave-uniform fixpoint: support stable -> exact tau
    tau = nt;
  }

  _Float16* wp = wout + (size_t)row * 4096;
#pragma unroll
  for (int i = 0; i < 8; ++i) {
    hv4 o;
#pragma unroll
    for (int j = 0; j < 4; ++j) {
      float d = fmaxf(x[i][j] - tau, 0.f);
      o[j] = (_Float16)(d * d);
    }
    *(hv4*)(wp + (size_t)(i * 64 + l) * 4) = o;
  }
}

// ---------------------------------------------------------------- generic NT GEMM
// C[M,N] = alpha * A[M,K] @ B[N,K]^T.  128x128 tile, 4 waves, 4x4 16x16x32 f16 MFMA.
// SPLIT: A/B have hi+lo fp16 pairs, 3-pass MFMA (~fp32 accuracy).
// nsplit>1: blockIdx.x = ntile*nsplit + kchunk; partial fp32 out at C32 + ks*partStride.
// dual: blockIdx.z selects job {B,outMode} vs {B2,outModeB} (for fused K/V projection).
// outMode 0: fp16   1: fp32   2: fp16 hi+lo
struct GemmParams {
  const _Float16 *A, *Alo, *B, *Blo, *B2;
  _Float16 *C16, *C16lo, *C16b;
  float* C32;
  const float* log_beta;
  int K, lda, ldb;
  long long aSB, aSH, bSH;
  long long cSB, cSH, cOsR, cOsC;
  long long cOsRb, cOsCb;
  long long partStride;
  int alphaMode, outMode, outModeB, nsplit, dual;
};

template <int SPLIT>
__global__ __launch_bounds__(256) void gemm_nt(GemmParams p) {
  __shared__ __align__(16) _Float16 As[128 * 32];
  __shared__ __align__(16) _Float16 Bs[128 * 32];
  __shared__ __align__(16) _Float16 Asl[SPLIT ? 128 * 32 : 8];
  __shared__ __align__(16) _Float16 Bsl[SPLIT ? 128 * 32 : 8];
  int t = threadIdx.x;
  int m0 = blockIdx.y * 128;
  int bx = blockIdx.x, n0, kbeg, kend, ks = 0;
  if (p.nsplit > 1) {
    ks = bx % p.nsplit;
    n0 = (bx / p.nsplit) * 128;
    int kl = p.K / p.nsplit;
    kbeg = ks * kl;
    kend = kbeg + kl;
  } else {
    n0 = bx * 128;
    kbeg = 0;
    kend = p.K;
  }
  int z = blockIdx.z, bidx, h, job = 0;
  if (p.dual) { job = z; bidx = 0; h = 0; }
  else { bidx = z >> 3; h = z & 7; }
  const _Float16* pA = p.A + bidx * p.aSB + h * p.aSH;
  const _Float16* pAl = SPLIT ? p.Alo + bidx * p.aSB + h * p.aSH : nullptr;
  const _Float16* pB = (job ? p.B2 : p.B) + h * p.bSH;
  const _Float16* pBl = SPLIT ? p.Blo + h * p.bSH : nullptr;

  fv4 acc[4][4] = {};
  int wv = t >> 6, l = t & 63, quad = l >> 4, lr = l & 15;
  int wm = (wv >> 1) * 64, wn = (wv & 1) * 64;
  int rl = l >> 2, cl = (l & 3) * 8;  // lane row-in-16 / halves offset for staging

  for (int k0 = kbeg; k0 < kend; k0 += 32) {
#pragma unroll
    for (int v = 0; v < 2; ++v) {
      int rb = wv * 16 + v * 64;  // wave-uniform row base
      size_t aOff = (size_t)(m0 + rb + rl) * p.lda + k0 + cl;
      size_t bOff = (size_t)(n0 + rb + rl) * p.ldb + k0 + cl;
      gll16(pA + aOff, &As[rb * 32]);
      gll16(pB + bOff, &Bs[rb * 32]);
      if (SPLIT) {
        gll16(pAl + aOff, &Asl[rb * 32]);
        gll16(pBl + bOff, &Bsl[rb * 32]);
      }
    }
    __syncthreads();  // drains vmcnt(0): global_load_lds complete
    half8 ah[4], bh[4];
#pragma unroll
    for (int mi = 0; mi < 4; ++mi) ah[mi] = *(const half8*)&As[(wm + mi * 16 + lr) * 32 + quad * 8];
#pragma unroll
    for (int ni = 0; ni < 4; ++ni) bh[ni] = *(const half8*)&Bs[(wn + ni * 16 + lr) * 32 + quad * 8];
#pragma unroll
    for (int mi = 0; mi < 4; ++mi)
#pragma unroll
      for (int ni = 0; ni < 4; ++ni)
        acc[mi][ni] = __builtin_amdgcn_mfma_f32_16x16x32_f16(ah[mi], bh[ni], acc[mi][ni], 0, 0, 0);
    if (SPLIT) {
      half8 al[4], bl[4];
#pragma unroll
      for (int mi = 0; mi < 4; ++mi) al[mi] = *(const half8*)&Asl[(wm + mi * 16 + lr) * 32 + quad * 8];
#pragma unroll
      for (int ni = 0; ni < 4; ++ni) bl[ni] = *(const half8*)&Bsl[(wn + ni * 16 + lr) * 32 + quad * 8];
#pragma unroll
      for (int mi = 0; mi < 4; ++mi)
#pragma unroll
        for (int ni = 0; ni < 4; ++ni) {
          acc[mi][ni] = __builtin_amdgcn_mfma_f32_16x16x32_f16(al[mi], bh[ni], acc[mi][ni], 0, 0, 0);
          acc[mi][ni] = __builtin_amdgcn_mfma_f32_16x16x32_f16(ah[mi], bl[ni], acc[mi][ni], 0, 0, 0);
        }
    }
    __syncthreads();
  }

  float alpha = p.alphaMode ? __expf(p.log_beta[h]) : 1.0f;
  int om = (p.dual && job) ? p.outModeB : p.outMode;
  _Float16* c16 = (p.dual && job) ? p.C16b : p.C16;
  long long osR = (p.dual && job) ? p.cOsRb : p.cOsR;
  long long osC = (p.dual && job) ? p.cOsCb : p.cOsC;
  float* c32 = p.C32 + (p.nsplit > 1 ? (long long)ks * p.partStride : 0);
  long long cOff = (long long)bidx * p.cSB + (long long)h * p.cSH;
#pragma unroll
  for (int mi = 0; mi < 4; ++mi)
#pragma unroll
    for (int ni = 0; ni < 4; ++ni) {
      int row = m0 + wm + mi * 16 + quad * 4;
      int col = n0 + wn + ni * 16 + lr;
#pragma unroll
      for (int r = 0; r < 4; ++r) {
        float val = acc[mi][ni][r] * alpha;
        long long idx = cOff + (long long)(row + r) * osR + (long long)col * osC;
        if (om == 1) {
          c32[idx] = val;
        } else if (om == 0) {
          c16[idx] = (_Float16)val;
        } else {
          _Float16 hi = (_Float16)val;
          c16[idx] = hi;
          p.C16lo[idx] = (_Float16)(val - (float)hi);
        }
      }
    }
}

// ---------------------------------------------------------------- host
extern "C" void kernel_launch(void* const* d_in, const int* in_sizes, int n_in,
                              void* d_out, int out_size, void* d_ws, size_t ws_size,
                              hipStream_t stream) {
  const float* hidden = (const float*)d_in[0];   // (2,1024,2048)
  const float* memory = (const float*)d_in[1];   // (2048,1024)
  const float* Wq = (const float*)d_in[2];       // (1024,2048)
  const float* Wk = (const float*)d_in[3];       // (1024,1024)
  const float* Wv = (const float*)d_in[4];       // (1024,1024)
  const float* Wo = (const float*)d_in[5];       // (2048,1024)
  const float* log_beta = (const float*)d_in[6]; // (8,)
  const float* g_state = (const float*)d_in[7];
  const float* b_state = (const float*)d_in[8];
  const float* g_mem = (const float*)d_in[9];
  const float* b_mem = (const float*)d_in[10];

  char* w = (char*)d_ws;
  auto alloc = [&](size_t bytes) {
    char* r = w;
    w += (bytes + 255) & ~(size_t)255;
    return r;
  };
  _Float16* wq16 = (_Float16*)alloc(2097152 * 2);
  _Float16* wk16 = (_Float16*)alloc(1048576 * 2);
  _Float16* wv16 = (_Float16*)alloc(1048576 * 2);
  _Float16* wo16 = (_Float16*)alloc(2097152 * 2);
  _Float16* lnh16 = (_Float16*)alloc(4194304 * 2);
  _Float16* mn16 = (_Float16*)alloc(2097152 * 2);
  _Float16* kph = (_Float16*)alloc(2097152 * 2);   // K proj hi (n, h*128+d)
  _Float16* kpl = (_Float16*)alloc(2097152 * 2);   // K proj lo
  _Float16* vt16 = (_Float16*)alloc(2097152 * 2);  // V^T (h*128+d, n)
  _Float16* xih = (_Float16*)alloc(2097152 * 2);   // xi hi (b*S+s, h*128+d)
  _Float16* xil = (_Float16*)alloc(2097152 * 2);   // xi lo
  float* parts = (float*)alloc((size_t)8 * 2097152 * 4);  // split-K partials
  float* scores = (float*)alloc((size_t)33554432 * 4);    // (b,h,s,n) fp32; w fp16 in-place

  ln_rows<<<2048, 256, 0, stream>>>(hidden, g_state, b_state, lnh16, 2048);
  ln_rows<<<2048, 256, 0, stream>>>(memory, g_mem, b_mem, mn16, 1024);
  cast_f16<<<2048, 256, 0, stream>>>(Wq, wq16, 2097152);
  cast_f16<<<1024, 256, 0, stream>>>(Wk, wk16, 1048576);
  cast_f16<<<1024, 256, 0, stream>>>(Wv, wv16, 1048576);
  cast_f16<<<2048, 256, 0, stream>>>(Wo, wo16, 2097152);

  // Q = ln(hidden) @ Wq^T  (split-K=2 partials -> reduce -> xi hi/lo)
  {
    GemmParams p{};
    p.A = lnh16; p.lda = 2048;
    p.B = wq16; p.ldb = 2048;
    p.K = 2048; p.nsplit = 2;
    p.C32 = parts; p.outMode = 1; p.partStride = 2097152;
    p.cOsR = 1024; p.cOsC = 1;
    gemm_nt<0><<<dim3(16, 16, 1), 256, 0, stream>>>(p);
    reduce_split<<<2048, 256, 0, stream>>>(parts, 2, 2097152, xih, xil, 2097152);
  }
  // K & V projections in one dual-job launch
  {
    GemmParams p{};
    p.A = mn16; p.lda = 1024;
    p.B = wk16; p.B2 = wv16; p.ldb = 1024;
    p.K = 1024; p.dual = 1;
    p.C16 = kph; p.C16lo = kpl; p.outMode = 2; p.cOsR = 1024; p.cOsC = 1;
    p.C16b = vt16; p.outModeB = 0; p.cOsRb = 1; p.cOsCb = 2048;
    gemm_nt<0><<<dim3(8, 16, 2), 256, 0, stream>>>(p);
  }

  for (int step = 0; step < 3; ++step) {
    // scores = beta_h * xi @ K^T  (hi/lo 3-pass, fp32 out)
    {
      GemmParams p{};
      p.A = xih; p.Alo = xil;
      p.lda = 1024; p.aSB = 1048576; p.aSH = 128;
      p.B = kph; p.Blo = kpl; p.ldb = 1024; p.bSH = 128;
      p.K = 128;
      p.alphaMode = 1; p.log_beta = log_beta;
      p.C32 = scores; p.outMode = 1;
      p.cSB = 16777216; p.cSH = 2097152;
      p.cOsR = 2048; p.cOsC = 1;
      gemm_nt<1><<<dim3(16, 8, 16), 256, 0, stream>>>(p);
    }
    entmax_w<<<4096, 256, 0, stream>>>(scores, (_Float16*)scores);
    // xi = w @ V  (plain fp16, split-K=2 partials -> reduce -> xi hi/lo)
    {
      GemmParams p{};
      p.A = (const _Float16*)scores;  // w fp16, stride 4096 halves
      p.lda = 4096; p.aSB = 33554432; p.aSH = 4194304;
      p.B = vt16; p.ldb = 2048; p.bSH = 262144;
      p.K = 2048; p.nsplit = 2;
      p.C32 = parts; p.outMode = 1; p.partStride = 2097152;
      p.cSB = 1048576; p.cSH = 128;
      p.cOsR = 1024; p.cOsC = 1;
      gemm_nt<0><<<dim3(2, 8, 16), 256, 0, stream>>>(p);
    }
    reduce_split<<<2048, 256, 0, stream>>>(parts, 2, 2097152, xih, xil, 2097152);
  }

  // out = xi @ Wo^T  (fp32 out)
  {
    GemmParams p{};
    p.A = xih; p.lda = 1024;
    p.B = wo16; p.ldb = 1024;
    p.K = 1024;
    p.C32 = (float*)d_out; p.outMode = 1;
    p.cOsR = 2048; p.cOsC = 1;
    gemm_nt<0><<<dim3(16, 16, 1), 256, 0, stream>>>(p);
  }
}

// Round 6
// 616.712 us; speedup vs baseline: 1.7915x; 1.0017x over previous
//
#include <hip/hip_runtime.h>

typedef _Float16 half8 __attribute__((ext_vector_type(8)));
typedef _Float16 hv4 __attribute__((ext_vector_type(4)));
typedef float fv4 __attribute__((ext_vector_type(4)));

typedef __attribute__((address_space(3))) unsigned lds_u32;
typedef const __attribute__((address_space(1))) unsigned glb_u32;

// async global->LDS, 16B per lane; dst is wave-uniform base, HW adds lane*16B
__device__ __forceinline__ void gll16(const void* g, void* l) {
  __builtin_amdgcn_global_load_lds((glb_u32*)g, (lds_u32*)l, 16, 0, 0);
}

// ---------------------------------------------------------------- LayerNorm
__global__ __launch_bounds__(256) void ln_rows(const float* __restrict__ in,
                                               const float* __restrict__ g,
                                               const float* __restrict__ bb,
                                               _Float16* __restrict__ out, int ncols) {
  __shared__ float sm[8];
  int row = blockIdx.x, t = threadIdx.x;
  const float* rp = in + (size_t)row * ncols;
  int nv = ncols >> 10;
  fv4 v[2];
  float s1 = 0.f, s2 = 0.f;
#pragma unroll
  for (int c = 0; c < 2; ++c)
    if (c < nv) {
      v[c] = *(const fv4*)(rp + c * 1024 + t * 4);
#pragma unroll
      for (int j = 0; j < 4; ++j) { s1 += v[c][j]; s2 += v[c][j] * v[c][j]; }
    }
#pragma unroll
  for (int off = 32; off > 0; off >>= 1) { s1 += __shfl_xor(s1, off, 64); s2 += __shfl_xor(s2, off, 64); }
  int w = t >> 6;
  if ((t & 63) == 0) { sm[w] = s1; sm[4 + w] = s2; }
  __syncthreads();
  s1 = sm[0] + sm[1] + sm[2] + sm[3];
  s2 = sm[4] + sm[5] + sm[6] + sm[7];
  float inv = 1.0f / (float)ncols;
  float mu = s1 * inv;
  float var = s2 * inv - mu * mu;
  float rstd = rsqrtf(var + 1e-5f);
#pragma unroll
  for (int c = 0; c < 2; ++c)
    if (c < nv) {
      int col = c * 1024 + t * 4;
      fv4 gg = *(const fv4*)(g + col);
      fv4 bv = *(const fv4*)(bb + col);
      hv4 o;
#pragma unroll
      for (int j = 0; j < 4; ++j) o[j] = (_Float16)(((v[c][j] - mu) * rstd) * gg[j] + bv[j]);
      *(hv4*)(out + (size_t)row * ncols + col) = o;
    }
}

// ---------------------------------------------------------------- fp32 -> fp16 cast
__global__ __launch_bounds__(256) void cast_f16(const float* __restrict__ in,
                                                _Float16* __restrict__ out, int n) {
  int i = (blockIdx.x * 256 + threadIdx.x) << 2;
  if (i < n) {
    fv4 f = *(const fv4*)(in + i);
    hv4 h;
#pragma unroll
    for (int j = 0; j < 4; ++j) h[j] = (_Float16)f[j];
    *(hv4*)(out + i) = h;
  }
}

// ---------------------------------------------------------------- sum ns partials -> hi/lo fp16
__global__ __launch_bounds__(256) void reduce_split(const float* __restrict__ parts, int ns,
                                                    long long stride, _Float16* __restrict__ hi,
                                                    _Float16* __restrict__ lo, int n) {
  int i = (blockIdx.x * 256 + threadIdx.x) << 2;
  if (i < n) {
    fv4 s = *(const fv4*)(parts + i);
    for (int j = 1; j < ns; ++j) {
      fv4 v = *(const fv4*)(parts + (size_t)j * stride + i);
      s += v;
    }
    hv4 h, l;
#pragma unroll
    for (int j = 0; j < 4; ++j) {
      h[j] = (_Float16)s[j];
      l[j] = (_Float16)(s[j] - (float)h[j]);
    }
    *(hv4*)(hi + i) = h;
    *(hv4*)(lo + i) = l;
  }
}

// ---------------------------------------------------------------- entmax-1.5: tau + w fp16
// One wave per score row (2048 fp16). Michelot exact support iteration from the valid
// superset S0 = {x > -1} (tau* >= -1). cnt via ballot+popcount (SALU). The fixpoint re-solves
// tau on the (fp16-rounded) row, so sum w = 1 holds by construction.
// Writes w = (max(0,(s-m)/2 - tau))^2 as fp16 IN-PLACE (same row, stride 2048) — wave reads
// the whole row into registers before storing, so the overwrite is race-free.
__global__ __launch_bounds__(256) void entmax_w(const _Float16* __restrict__ scores,
                                                _Float16* __restrict__ wout) {
  int row = blockIdx.x * 4 + (threadIdx.x >> 6);
  int l = threadIdx.x & 63;
  const half8* sp = (const half8*)(scores + (size_t)row * 2048);
  half8 hx[4];
#pragma unroll
  for (int i = 0; i < 4; ++i) hx[i] = sp[i * 64 + l];
  fv4 x[8], xx[8];
#pragma unroll
  for (int i = 0; i < 4; ++i)
#pragma unroll
    for (int j = 0; j < 8; ++j) x[i * 2 + (j >> 2)][j & 3] = (float)hx[i][j];
  float m = x[0][0];
#pragma unroll
  for (int i = 0; i < 8; ++i)
#pragma unroll
    for (int j = 0; j < 4; ++j) m = fmaxf(m, x[i][j]);
#pragma unroll
  for (int off = 32; off > 0; off >>= 1) m = fmaxf(m, __shfl_xor(m, off, 64));
#pragma unroll
  for (int i = 0; i < 8; ++i)
#pragma unroll
    for (int j = 0; j < 4; ++j) {
      x[i][j] = (x[i][j] - m) * 0.5f;
      xx[i][j] = x[i][j] * x[i][j];
    }

  float tau = -1.0f;  // tau* in [-1, 0]; S0 = {x > -1} is a superset of the support
  for (int it = 0; it < 12; ++it) {
    float s1 = 0.f, s2 = 0.f;
    int cnti = 0;
#pragma unroll
    for (int i = 0; i < 8; ++i)
#pragma unroll
      for (int j = 0; j < 4; ++j) {
        bool a = x[i][j] > tau;
        cnti += (int)__builtin_popcountll(__ballot(a));  // SALU: s_bcnt1 + s_add
        s1 += a ? x[i][j] : 0.f;
        s2 += a ? xx[i][j] : 0.f;
      }
#pragma unroll
    for (int off = 32; off > 0; off >>= 1) {
      s1 += __shfl_xor(s1, off, 64);
      s2 += __shfl_xor(s2, off, 64);
    }
    float cnt = (float)cnti;
    float mean = s1 / cnt;
    float ss = s2 - s1 * mean;  // = sum_S (x - mean)^2
    float nt = mean - sqrtf(fmaxf((1.0f - ss) / cnt, 0.0f));
    if (nt == tau) break;  // wave-uniform fixpoint: support stable -> exact tau
    tau = nt;
  }

  half8* wp = (half8*)(wout + (size_t)row * 2048);
#pragma unroll
  for (int i = 0; i < 4; ++i) {
    half8 o;
#pragma unroll
    for (int j = 0; j < 8; ++j) {
      float d = fmaxf(x[i * 2 + (j >> 2)][j & 3] - tau, 0.f);
      o[j] = (_Float16)(d * d);
    }
    wp[i * 64 + l] = o;
  }
}

// ---------------------------------------------------------------- generic NT GEMM
// C[M,N] = alpha * A[M,K] @ B[N,K]^T.  128x128 tile, 4 waves, 4x4 16x16x32 f16 MFMA.
// SPLIT: A/B have hi+lo fp16 pairs, 3-pass MFMA (~fp32 accuracy).
// nsplit>1: blockIdx.x = ntile*nsplit + kchunk; partial fp32 out at C32 + ks*partStride.
// dual: blockIdx.z selects job {B,outMode} vs {B2,outModeB} (for fused K/V projection).
// outMode 0: fp16   1: fp32   2: fp16 hi+lo
struct GemmParams {
  const _Float16 *A, *Alo, *B, *Blo, *B2;
  _Float16 *C16, *C16lo, *C16b;
  float* C32;
  const float* log_beta;
  int K, lda, ldb;
  long long aSB, aSH, bSH;
  long long cSB, cSH, cOsR, cOsC;
  long long cOsRb, cOsCb;
  long long partStride;
  int alphaMode, outMode, outModeB, nsplit, dual;
};

template <int SPLIT>
__global__ __launch_bounds__(256) void gemm_nt(GemmParams p) {
  __shared__ __align__(16) _Float16 As[128 * 32];
  __shared__ __align__(16) _Float16 Bs[128 * 32];
  __shared__ __align__(16) _Float16 Asl[SPLIT ? 128 * 32 : 8];
  __shared__ __align__(16) _Float16 Bsl[SPLIT ? 128 * 32 : 8];
  int t = threadIdx.x;
  int m0 = blockIdx.y * 128;
  int bx = blockIdx.x, n0, kbeg, kend, ks = 0;
  if (p.nsplit > 1) {
    ks = bx % p.nsplit;
    n0 = (bx / p.nsplit) * 128;
    int kl = p.K / p.nsplit;
    kbeg = ks * kl;
    kend = kbeg + kl;
  } else {
    n0 = bx * 128;
    kbeg = 0;
    kend = p.K;
  }
  int z = blockIdx.z, bidx, h, job = 0;
  if (p.dual) { job = z; bidx = 0; h = 0; }
  else { bidx = z >> 3; h = z & 7; }
  const _Float16* pA = p.A + bidx * p.aSB + h * p.aSH;
  const _Float16* pAl = SPLIT ? p.Alo + bidx * p.aSB + h * p.aSH : nullptr;
  const _Float16* pB = (job ? p.B2 : p.B) + h * p.bSH;
  const _Float16* pBl = SPLIT ? p.Blo + h * p.bSH : nullptr;

  fv4 acc[4][4] = {};
  int wv = t >> 6, l = t & 63, quad = l >> 4, lr = l & 15;
  int wm = (wv >> 1) * 64, wn = (wv & 1) * 64;
  int rl = l >> 2, cl = (l & 3) * 8;  // lane row-in-16 / halves offset for staging

  for (int k0 = kbeg; k0 < kend; k0 += 32) {
#pragma unroll
    for (int v = 0; v < 2; ++v) {
      int rb = wv * 16 + v * 64;  // wave-uniform row base
      size_t aOff = (size_t)(m0 + rb + rl) * p.lda + k0 + cl;
      size_t bOff = (size_t)(n0 + rb + rl) * p.ldb + k0 + cl;
      gll16(pA + aOff, &As[rb * 32]);
      gll16(pB + bOff, &Bs[rb * 32]);
      if (SPLIT) {
        gll16(pAl + aOff, &Asl[rb * 32]);
        gll16(pBl + bOff, &Bsl[rb * 32]);
      }
    }
    __syncthreads();  // drains vmcnt(0): global_load_lds complete
    half8 ah[4], bh[4];
#pragma unroll
    for (int mi = 0; mi < 4; ++mi) ah[mi] = *(const half8*)&As[(wm + mi * 16 + lr) * 32 + quad * 8];
#pragma unroll
    for (int ni = 0; ni < 4; ++ni) bh[ni] = *(const half8*)&Bs[(wn + ni * 16 + lr) * 32 + quad * 8];
#pragma unroll
    for (int mi = 0; mi < 4; ++mi)
#pragma unroll
      for (int ni = 0; ni < 4; ++ni)
        acc[mi][ni] = __builtin_amdgcn_mfma_f32_16x16x32_f16(ah[mi], bh[ni], acc[mi][ni], 0, 0, 0);
    if (SPLIT) {
      half8 al[4], bl[4];
#pragma unroll
      for (int mi = 0; mi < 4; ++mi) al[mi] = *(const half8*)&Asl[(wm + mi * 16 + lr) * 32 + quad * 8];
#pragma unroll
      for (int ni = 0; ni < 4; ++ni) bl[ni] = *(const half8*)&Bsl[(wn + ni * 16 + lr) * 32 + quad * 8];
#pragma unroll
      for (int mi = 0; mi < 4; ++mi)
#pragma unroll
        for (int ni = 0; ni < 4; ++ni) {
          acc[mi][ni] = __builtin_amdgcn_mfma_f32_16x16x32_f16(al[mi], bh[ni], acc[mi][ni], 0, 0, 0);
          acc[mi][ni] = __builtin_amdgcn_mfma_f32_16x16x32_f16(ah[mi], bl[ni], acc[mi][ni], 0, 0, 0);
        }
    }
    __syncthreads();
  }

  float alpha = p.alphaMode ? __expf(p.log_beta[h]) : 1.0f;
  int om = (p.dual && job) ? p.outModeB : p.outMode;
  _Float16* c16 = (p.dual && job) ? p.C16b : p.C16;
  long long osR = (p.dual && job) ? p.cOsRb : p.cOsR;
  long long osC = (p.dual && job) ? p.cOsCb : p.cOsC;
  float* c32 = p.C32 + (p.nsplit > 1 ? (long long)ks * p.partStride : 0);
  long long cOff = (long long)bidx * p.cSB + (long long)h * p.cSH;
#pragma unroll
  for (int mi = 0; mi < 4; ++mi)
#pragma unroll
    for (int ni = 0; ni < 4; ++ni) {
      int row = m0 + wm + mi * 16 + quad * 4;
      int col = n0 + wn + ni * 16 + lr;
#pragma unroll
      for (int r = 0; r < 4; ++r) {
        float val = acc[mi][ni][r] * alpha;
        long long idx = cOff + (long long)(row + r) * osR + (long long)col * osC;
        if (om == 1) {
          c32[idx] = val;
        } else if (om == 0) {
          c16[idx] = (_Float16)val;
        } else {
          _Float16 hi = (_Float16)val;
          c16[idx] = hi;
          p.C16lo[idx] = (_Float16)(val - (float)hi);
        }
      }
    }
}

// ---------------------------------------------------------------- host
extern "C" void kernel_launch(void* const* d_in, const int* in_sizes, int n_in,
                              void* d_out, int out_size, void* d_ws, size_t ws_size,
                              hipStream_t stream) {
  const float* hidden = (const float*)d_in[0];   // (2,1024,2048)
  const float* memory = (const float*)d_in[1];   // (2048,1024)
  const float* Wq = (const float*)d_in[2];       // (1024,2048)
  const float* Wk = (const float*)d_in[3];       // (1024,1024)
  const float* Wv = (const float*)d_in[4];       // (1024,1024)
  const float* Wo = (const float*)d_in[5];       // (2048,1024)
  const float* log_beta = (const float*)d_in[6]; // (8,)
  const float* g_state = (const float*)d_in[7];
  const float* b_state = (const float*)d_in[8];
  const float* g_mem = (const float*)d_in[9];
  const float* b_mem = (const float*)d_in[10];

  char* w = (char*)d_ws;
  auto alloc = [&](size_t bytes) {
    char* r = w;
    w += (bytes + 255) & ~(size_t)255;
    return r;
  };
  _Float16* wq16 = (_Float16*)alloc(2097152 * 2);
  _Float16* wk16 = (_Float16*)alloc(1048576 * 2);
  _Float16* wv16 = (_Float16*)alloc(1048576 * 2);
  _Float16* wo16 = (_Float16*)alloc(2097152 * 2);
  _Float16* lnh16 = (_Float16*)alloc(4194304 * 2);
  _Float16* mn16 = (_Float16*)alloc(2097152 * 2);
  _Float16* kph = (_Float16*)alloc(2097152 * 2);   // K proj hi (n, h*128+d)
  _Float16* kpl = (_Float16*)alloc(2097152 * 2);   // K proj lo
  _Float16* vt16 = (_Float16*)alloc(2097152 * 2);  // V^T (h*128+d, n)
  _Float16* xih = (_Float16*)alloc(2097152 * 2);   // xi hi (b*S+s, h*128+d)
  _Float16* xil = (_Float16*)alloc(2097152 * 2);   // xi lo
  float* parts = (float*)alloc((size_t)8 * 2097152 * 4);     // split-K partials
  _Float16* scores16 = (_Float16*)alloc((size_t)33554432 * 2);  // (b,h,s,n) fp16; w in-place

  ln_rows<<<2048, 256, 0, stream>>>(hidden, g_state, b_state, lnh16, 2048);
  ln_rows<<<2048, 256, 0, stream>>>(memory, g_mem, b_mem, mn16, 1024);
  cast_f16<<<2048, 256, 0, stream>>>(Wq, wq16, 2097152);
  cast_f16<<<1024, 256, 0, stream>>>(Wk, wk16, 1048576);
  cast_f16<<<1024, 256, 0, stream>>>(Wv, wv16, 1048576);
  cast_f16<<<2048, 256, 0, stream>>>(Wo, wo16, 2097152);

  // Q = ln(hidden) @ Wq^T  (split-K=2 partials -> reduce -> xi hi/lo)
  {
    GemmParams p{};
    p.A = lnh16; p.lda = 2048;
    p.B = wq16; p.ldb = 2048;
    p.K = 2048; p.nsplit = 2;
    p.C32 = parts; p.outMode = 1; p.partStride = 2097152;
    p.cOsR = 1024; p.cOsC = 1;
    gemm_nt<0><<<dim3(16, 16, 1), 256, 0, stream>>>(p);
    reduce_split<<<2048, 256, 0, stream>>>(parts, 2, 2097152, xih, xil, 2097152);
  }
  // K & V projections in one dual-job launch
  {
    GemmParams p{};
    p.A = mn16; p.lda = 1024;
    p.B = wk16; p.B2 = wv16; p.ldb = 1024;
    p.K = 1024; p.dual = 1;
    p.C16 = kph; p.C16lo = kpl; p.outMode = 2; p.cOsR = 1024; p.cOsC = 1;
    p.C16b = vt16; p.outModeB = 0; p.cOsRb = 1; p.cOsCb = 2048;
    gemm_nt<0><<<dim3(8, 16, 2), 256, 0, stream>>>(p);
  }

  for (int step = 0; step < 3; ++step) {
    // scores = beta_h * xi @ K^T  (hi/lo 3-pass, fp16 out)
    {
      GemmParams p{};
      p.A = xih; p.Alo = xil;
      p.lda = 1024; p.aSB = 1048576; p.aSH = 128;
      p.B = kph; p.Blo = kpl; p.ldb = 1024; p.bSH = 128;
      p.K = 128;
      p.alphaMode = 1; p.log_beta = log_beta;
      p.C16 = scores16; p.outMode = 0;
      p.cSB = 16777216; p.cSH = 2097152;
      p.cOsR = 2048; p.cOsC = 1;
      gemm_nt<1><<<dim3(16, 8, 16), 256, 0, stream>>>(p);
    }
    entmax_w<<<4096, 256, 0, stream>>>(scores16, scores16);
    // xi = w @ V  (plain fp16, split-K=2 partials -> reduce -> xi hi/lo)
    {
      GemmParams p{};
      p.A = scores16;  // w fp16, dense rows stride 2048
      p.lda = 2048; p.aSB = 16777216; p.aSH = 2097152;
      p.B = vt16; p.ldb = 2048; p.bSH = 262144;
      p.K = 2048; p.nsplit = 2;
      p.C32 = parts; p.outMode = 1; p.partStride = 2097152;
      p.cSB = 1048576; p.cSH = 128;
      p.cOsR = 1024; p.cOsC = 1;
      gemm_nt<0><<<dim3(2, 8, 16), 256, 0, stream>>>(p);
    }
    reduce_split<<<2048, 256, 0, stream>>>(parts, 2, 2097152, xih, xil, 2097152);
  }

  // out = xi @ Wo^T  (fp32 out)
  {
    GemmParams p{};
    p.A = xih; p.lda = 1024;
    p.B = wo16; p.ldb = 1024;
    p.K = 1024;
    p.C32 = (float*)d_out; p.outMode = 1;
    p.cOsR = 2048; p.cOsC = 1;
    gemm_nt<0><<<dim3(16, 16, 1), 256, 0, stream>>>(p);
  }
}

// Round 7
// 493.700 us; speedup vs baseline: 2.2378x; 1.2492x over previous
//
#include <hip/hip_runtime.h>

typedef _Float16 half8 __attribute__((ext_vector_type(8)));
typedef _Float16 hv4 __attribute__((ext_vector_type(4)));
typedef float fv4 __attribute__((ext_vector_type(4)));

typedef __attribute__((address_space(3))) unsigned lds_u32;
typedef const __attribute__((address_space(1))) unsigned glb_u32;

// async global->LDS, 16B per lane; dst is wave-uniform base, HW adds lane*16B
__device__ __forceinline__ void gll16(const void* g, void* l) {
  __builtin_amdgcn_global_load_lds((glb_u32*)g, (lds_u32*)l, 16, 0, 0);
}

// ---------------------------------------------------------------- LayerNorm
__global__ __launch_bounds__(256) void ln_rows(const float* __restrict__ in,
                                               const float* __restrict__ g,
                                               const float* __restrict__ bb,
                                               _Float16* __restrict__ out, int ncols) {
  __shared__ float sm[8];
  int row = blockIdx.x, t = threadIdx.x;
  const float* rp = in + (size_t)row * ncols;
  int nv = ncols >> 10;
  fv4 v[2];
  float s1 = 0.f, s2 = 0.f;
#pragma unroll
  for (int c = 0; c < 2; ++c)
    if (c < nv) {
      v[c] = *(const fv4*)(rp + c * 1024 + t * 4);
#pragma unroll
      for (int j = 0; j < 4; ++j) { s1 += v[c][j]; s2 += v[c][j] * v[c][j]; }
    }
#pragma unroll
  for (int off = 32; off > 0; off >>= 1) { s1 += __shfl_xor(s1, off, 64); s2 += __shfl_xor(s2, off, 64); }
  int w = t >> 6;
  if ((t & 63) == 0) { sm[w] = s1; sm[4 + w] = s2; }
  __syncthreads();
  s1 = sm[0] + sm[1] + sm[2] + sm[3];
  s2 = sm[4] + sm[5] + sm[6] + sm[7];
  float inv = 1.0f / (float)ncols;
  float mu = s1 * inv;
  float var = s2 * inv - mu * mu;
  float rstd = rsqrtf(var + 1e-5f);
#pragma unroll
  for (int c = 0; c < 2; ++c)
    if (c < nv) {
      int col = c * 1024 + t * 4;
      fv4 gg = *(const fv4*)(g + col);
      fv4 bv = *(const fv4*)(bb + col);
      hv4 o;
#pragma unroll
      for (int j = 0; j < 4; ++j) o[j] = (_Float16)(((v[c][j] - mu) * rstd) * gg[j] + bv[j]);
      *(hv4*)(out + (size_t)row * ncols + col) = o;
    }
}

// ---------------------------------------------------------------- fp32 -> fp16 cast
__global__ __launch_bounds__(256) void cast_f16(const float* __restrict__ in,
                                                _Float16* __restrict__ out, int n) {
  int i = (blockIdx.x * 256 + threadIdx.x) << 2;
  if (i < n) {
    fv4 f = *(const fv4*)(in + i);
    hv4 h;
#pragma unroll
    for (int j = 0; j < 4; ++j) h[j] = (_Float16)f[j];
    *(hv4*)(out + i) = h;
  }
}

// ---------------------------------------------------------------- sum ns partials -> fp16
__global__ __launch_bounds__(256) void reduce_split(const float* __restrict__ parts, int ns,
                                                    long long stride,
                                                    _Float16* __restrict__ hi, int n) {
  int i = (blockIdx.x * 256 + threadIdx.x) << 2;
  if (i < n) {
    fv4 s = *(const fv4*)(parts + i);
    for (int j = 1; j < ns; ++j) {
      fv4 v = *(const fv4*)(parts + (size_t)j * stride + i);
      s += v;
    }
    hv4 h;
#pragma unroll
    for (int j = 0; j < 4; ++j) h[j] = (_Float16)s[j];
    *(hv4*)(hi + i) = h;
  }
}

// ---------------------------------------------------------------- entmax-1.5: tau + w fp16
// One wave per score row (2048 fp16). Michelot exact support iteration from superset
// S0={x>-1} (tau* in [-1,0]); support shrinks monotonically, so after the count drops
// <=512 the survivors are compacted into LDS (ballot prefix-sum) and iterated cheaply
// (8 elems/lane instead of 32). Fallback: full-register scans for flat rows. Fixpoint
// tau is exact on the fp16-rounded row, so sum w = 1 by construction.
// Writes w = (max(0,(s-m)/2 - tau))^2 fp16 in-place (race-free: row read fully first).
__global__ __launch_bounds__(256) void entmax_w(const _Float16* __restrict__ scores,
                                                _Float16* __restrict__ wout) {
  __shared__ float comp[4][512];
  int wid = threadIdx.x >> 6;
  int row = blockIdx.x * 4 + wid;
  int l = threadIdx.x & 63;
  unsigned long long lmask = (1ull << l) - 1ull;
  const half8* sp = (const half8*)(scores + (size_t)row * 2048);
  half8 hx[4];
#pragma unroll
  for (int i = 0; i < 4; ++i) hx[i] = sp[i * 64 + l];
  fv4 x[8], xx[8];
#pragma unroll
  for (int i = 0; i < 4; ++i)
#pragma unroll
    for (int j = 0; j < 8; ++j) x[i * 2 + (j >> 2)][j & 3] = (float)hx[i][j];
  float m = x[0][0];
#pragma unroll
  for (int i = 0; i < 8; ++i)
#pragma unroll
    for (int j = 0; j < 4; ++j) m = fmaxf(m, x[i][j]);
#pragma unroll
  for (int off = 32; off > 0; off >>= 1) m = fmaxf(m, __shfl_xor(m, off, 64));
#pragma unroll
  for (int i = 0; i < 8; ++i)
#pragma unroll
    for (int j = 0; j < 4; ++j) {
      x[i][j] = (x[i][j] - m) * 0.5f;
      xx[i][j] = x[i][j] * x[i][j];
    }

  float tau = -1.0f;
  bool fixed = false;
  int cnti = 2048;
  // phase 1: full-register scans until support fits in the compaction buffer
  for (int it = 0; it < 6 && !fixed; ++it) {
    float s1 = 0.f, s2 = 0.f;
    cnti = 0;
#pragma unroll
    for (int i = 0; i < 8; ++i)
#pragma unroll
      for (int j = 0; j < 4; ++j) {
        bool a = x[i][j] > tau;
        cnti += (int)__builtin_popcountll(__ballot(a));
        s1 += a ? x[i][j] : 0.f;
        s2 += a ? xx[i][j] : 0.f;
      }
#pragma unroll
    for (int off = 32; off > 0; off >>= 1) {
      s1 += __shfl_xor(s1, off, 64);
      s2 += __shfl_xor(s2, off, 64);
    }
    float cnt = (float)cnti;
    float mean = s1 / cnt;
    float ss = s2 - s1 * mean;
    float nt = mean - sqrtf(fmaxf((1.0f - ss) / cnt, 0.0f));
    if (nt == tau) fixed = true;
    else tau = nt;
    if (cnti <= 512) break;
  }
  if (!fixed) {
    if (cnti <= 512) {
      // compact survivors {x > tau} into LDS (count <= cnti <= 512)
      int base = 0;
#pragma unroll
      for (int i = 0; i < 8; ++i)
#pragma unroll
        for (int j = 0; j < 4; ++j) {
          bool a = x[i][j] > tau;
          unsigned long long mk = __ballot(a);
          if (a) comp[wid][base + (int)__builtin_popcountll(mk & lmask)] = x[i][j];
          base += (int)__builtin_popcountll(mk);
        }
      float y[8], yy[8];
#pragma unroll
      for (int r = 0; r < 8; ++r) {
        int idx = r * 64 + l;
        float v = (idx < base) ? comp[wid][idx] : -2.0f;  // sentinel < -1 <= tau: never active
        y[r] = v;
        yy[r] = v * v;
      }
      for (int it = 0; it < 10 && !fixed; ++it) {
        float s1 = 0.f, s2 = 0.f;
        int c = 0;
#pragma unroll
        for (int r = 0; r < 8; ++r) {
          bool a = y[r] > tau;
          c += (int)__builtin_popcountll(__ballot(a));
          s1 += a ? y[r] : 0.f;
          s2 += a ? yy[r] : 0.f;
        }
#pragma unroll
        for (int off = 32; off > 0; off >>= 1) {
          s1 += __shfl_xor(s1, off, 64);
          s2 += __shfl_xor(s2, off, 64);
        }
        float cnt = (float)c;
        float mean = s1 / cnt;
        float ss = s2 - s1 * mean;
        float nt = mean - sqrtf(fmaxf((1.0f - ss) / cnt, 0.0f));
        if (nt == tau) fixed = true;
        else tau = nt;
      }
    } else {
      // pathological flat row: keep full scans
      for (int it = 0; it < 8 && !fixed; ++it) {
        float s1 = 0.f, s2 = 0.f;
        int c = 0;
#pragma unroll
        for (int i = 0; i < 8; ++i)
#pragma unroll
          for (int j = 0; j < 4; ++j) {
            bool a = x[i][j] > tau;
            c += (int)__builtin_popcountll(__ballot(a));
            s1 += a ? x[i][j] : 0.f;
            s2 += a ? xx[i][j] : 0.f;
          }
#pragma unroll
        for (int off = 32; off > 0; off >>= 1) {
          s1 += __shfl_xor(s1, off, 64);
          s2 += __shfl_xor(s2, off, 64);
        }
        float cnt = (float)c;
        float mean = s1 / cnt;
        float ss = s2 - s1 * mean;
        float nt = mean - sqrtf(fmaxf((1.0f - ss) / cnt, 0.0f));
        if (nt == tau) fixed = true;
        else tau = nt;
      }
    }
  }

  half8* wp = (half8*)(wout + (size_t)row * 2048);
#pragma unroll
  for (int i = 0; i < 4; ++i) {
    half8 o;
#pragma unroll
    for (int j = 0; j < 8; ++j) {
      float d = fmaxf(x[i * 2 + (j >> 2)][j & 3] - tau, 0.f);
      o[j] = (_Float16)(d * d);
    }
    wp[i * 64 + l] = o;
  }
}

// ---------------------------------------------------------------- generic NT GEMM
// C[M,N] = alpha * A[M,K] @ B[N,K]^T.  128x128 tile, 4 waves, 4x4 16x16x32 f16 MFMA.
// nsplit>1: blockIdx.x = ntile*nsplit + kchunk; partial fp32 out at C32 + ks*partStride.
// dual: blockIdx.z selects job {B,outMode} vs {B2,outModeB}.
// outMode 0: fp16   1: fp32
struct GemmParams {
  const _Float16 *A, *B, *B2;
  _Float16 *C16, *C16b;
  float* C32;
  const float* log_beta;
  int K, lda, ldb;
  long long aSB, aSH, bSH;
  long long cSB, cSH, cOsR, cOsC;
  long long cOsRb, cOsCb;
  long long partStride;
  int alphaMode, outMode, outModeB, nsplit, dual;
};

__global__ __launch_bounds__(256) void gemm_nt(GemmParams p) {
  __shared__ __align__(16) _Float16 As[128 * 32];
  __shared__ __align__(16) _Float16 Bs[128 * 32];
  int t = threadIdx.x;
  int m0 = blockIdx.y * 128;
  int bx = blockIdx.x, n0, kbeg, kend, ks = 0;
  if (p.nsplit > 1) {
    ks = bx % p.nsplit;
    n0 = (bx / p.nsplit) * 128;
    int kl = p.K / p.nsplit;
    kbeg = ks * kl;
    kend = kbeg + kl;
  } else {
    n0 = bx * 128;
    kbeg = 0;
    kend = p.K;
  }
  int z = blockIdx.z, bidx, h, job = 0;
  if (p.dual) { job = z; bidx = 0; h = 0; }
  else { bidx = z >> 3; h = z & 7; }
  const _Float16* pA = p.A + bidx * p.aSB + h * p.aSH;
  const _Float16* pB = (job ? p.B2 : p.B) + h * p.bSH;

  fv4 acc[4][4] = {};
  int wv = t >> 6, l = t & 63, quad = l >> 4, lr = l & 15;
  int wm = (wv >> 1) * 64, wn = (wv & 1) * 64;
  int rl = l >> 2, cl = (l & 3) * 8;  // lane row-in-16 / halves offset for staging

  for (int k0 = kbeg; k0 < kend; k0 += 32) {
#pragma unroll
    for (int v = 0; v < 2; ++v) {
      int rb = wv * 16 + v * 64;  // wave-uniform row base
      size_t aOff = (size_t)(m0 + rb + rl) * p.lda + k0 + cl;
      size_t bOff = (size_t)(n0 + rb + rl) * p.ldb + k0 + cl;
      gll16(pA + aOff, &As[rb * 32]);
      gll16(pB + bOff, &Bs[rb * 32]);
    }
    __syncthreads();  // drains vmcnt(0): global_load_lds complete
    half8 ah[4], bh[4];
#pragma unroll
    for (int mi = 0; mi < 4; ++mi) ah[mi] = *(const half8*)&As[(wm + mi * 16 + lr) * 32 + quad * 8];
#pragma unroll
    for (int ni = 0; ni < 4; ++ni) bh[ni] = *(const half8*)&Bs[(wn + ni * 16 + lr) * 32 + quad * 8];
#pragma unroll
    for (int mi = 0; mi < 4; ++mi)
#pragma unroll
      for (int ni = 0; ni < 4; ++ni)
        acc[mi][ni] = __builtin_amdgcn_mfma_f32_16x16x32_f16(ah[mi], bh[ni], acc[mi][ni], 0, 0, 0);
    __syncthreads();
  }

  float alpha = p.alphaMode ? __expf(p.log_beta[h]) : 1.0f;
  int om = (p.dual && job) ? p.outModeB : p.outMode;
  _Float16* c16 = (p.dual && job) ? p.C16b : p.C16;
  long long osR = (p.dual && job) ? p.cOsRb : p.cOsR;
  long long osC = (p.dual && job) ? p.cOsCb : p.cOsC;
  float* c32 = p.C32 + (p.nsplit > 1 ? (long long)ks * p.partStride : 0);
  long long cOff = (long long)bidx * p.cSB + (long long)h * p.cSH;
#pragma unroll
  for (int mi = 0; mi < 4; ++mi)
#pragma unroll
    for (int ni = 0; ni < 4; ++ni) {
      int row = m0 + wm + mi * 16 + quad * 4;
      int col = n0 + wn + ni * 16 + lr;
#pragma unroll
      for (int r = 0; r < 4; ++r) {
        float val = acc[mi][ni][r] * alpha;
        long long idx = cOff + (long long)(row + r) * osR + (long long)col * osC;
        if (om == 1) c32[idx] = val;
        else c16[idx] = (_Float16)val;
      }
    }
}

// ---------------------------------------------------------------- host
extern "C" void kernel_launch(void* const* d_in, const int* in_sizes, int n_in,
                              void* d_out, int out_size, void* d_ws, size_t ws_size,
                              hipStream_t stream) {
  const float* hidden = (const float*)d_in[0];   // (2,1024,2048)
  const float* memory = (const float*)d_in[1];   // (2048,1024)
  const float* Wq = (const float*)d_in[2];       // (1024,2048)
  const float* Wk = (const float*)d_in[3];       // (1024,1024)
  const float* Wv = (const float*)d_in[4];       // (1024,1024)
  const float* Wo = (const float*)d_in[5];       // (2048,1024)
  const float* log_beta = (const float*)d_in[6]; // (8,)
  const float* g_state = (const float*)d_in[7];
  const float* b_state = (const float*)d_in[8];
  const float* g_mem = (const float*)d_in[9];
  const float* b_mem = (const float*)d_in[10];

  char* w = (char*)d_ws;
  auto alloc = [&](size_t bytes) {
    char* r = w;
    w += (bytes + 255) & ~(size_t)255;
    return r;
  };
  _Float16* wq16 = (_Float16*)alloc(2097152 * 2);
  _Float16* wk16 = (_Float16*)alloc(1048576 * 2);
  _Float16* wv16 = (_Float16*)alloc(1048576 * 2);
  _Float16* wo16 = (_Float16*)alloc(2097152 * 2);
  _Float16* lnh16 = (_Float16*)alloc(4194304 * 2);
  _Float16* mn16 = (_Float16*)alloc(2097152 * 2);
  _Float16* kph = (_Float16*)alloc(2097152 * 2);   // K proj (n, h*128+d)
  _Float16* vt16 = (_Float16*)alloc(2097152 * 2);  // V^T (h*128+d, n)
  _Float16* xih = (_Float16*)alloc(2097152 * 2);   // xi (b*S+s, h*128+d)
  float* parts = (float*)alloc((size_t)8 * 2097152 * 4);        // split-K partials
  _Float16* scores16 = (_Float16*)alloc((size_t)33554432 * 2);  // (b,h,s,n) fp16; w in-place

  ln_rows<<<2048, 256, 0, stream>>>(hidden, g_state, b_state, lnh16, 2048);
  ln_rows<<<2048, 256, 0, stream>>>(memory, g_mem, b_mem, mn16, 1024);
  cast_f16<<<2048, 256, 0, stream>>>(Wq, wq16, 2097152);
  cast_f16<<<1024, 256, 0, stream>>>(Wk, wk16, 1048576);
  cast_f16<<<1024, 256, 0, stream>>>(Wv, wv16, 1048576);
  cast_f16<<<2048, 256, 0, stream>>>(Wo, wo16, 2097152);

  // Q = ln(hidden) @ Wq^T  (split-K=2 partials -> reduce -> xi fp16)
  {
    GemmParams p{};
    p.A = lnh16; p.lda = 2048;
    p.B = wq16; p.ldb = 2048;
    p.K = 2048; p.nsplit = 2;
    p.C32 = parts; p.outMode = 1; p.partStride = 2097152;
    p.cOsR = 1024; p.cOsC = 1;
    gemm_nt<<<dim3(16, 16, 1), 256, 0, stream>>>(p);
    reduce_split<<<2048, 256, 0, stream>>>(parts, 2, 2097152, xih, 2097152);
  }
  // K & V projections in one dual-job launch (both plain fp16)
  {
    GemmParams p{};
    p.A = mn16; p.lda = 1024;
    p.B = wk16; p.B2 = wv16; p.ldb = 1024;
    p.K = 1024; p.dual = 1;
    p.C16 = kph; p.outMode = 0; p.cOsR = 1024; p.cOsC = 1;
    p.C16b = vt16; p.outModeB = 0; p.cOsRb = 1; p.cOsCb = 2048;
    gemm_nt<<<dim3(8, 16, 2), 256, 0, stream>>>(p);
  }

  for (int step = 0; step < 3; ++step) {
    // scores = beta_h * xi @ K^T  (plain fp16, fp16 out)
    {
      GemmParams p{};
      p.A = xih;
      p.lda = 1024; p.aSB = 1048576; p.aSH = 128;
      p.B = kph; p.ldb = 1024; p.bSH = 128;
      p.K = 128;
      p.alphaMode = 1; p.log_beta = log_beta;
      p.C16 = scores16; p.outMode = 0;
      p.cSB = 16777216; p.cSH = 2097152;
      p.cOsR = 2048; p.cOsC = 1;
      gemm_nt<<<dim3(16, 8, 16), 256, 0, stream>>>(p);
    }
    entmax_w<<<4096, 256, 0, stream>>>(scores16, scores16);
    // xi = w @ V  (plain fp16, split-K=4 partials -> reduce -> xi fp16)
    {
      GemmParams p{};
      p.A = scores16;  // w fp16, dense rows stride 2048
      p.lda = 2048; p.aSB = 16777216; p.aSH = 2097152;
      p.B = vt16; p.ldb = 2048; p.bSH = 262144;
      p.K = 2048; p.nsplit = 4;
      p.C32 = parts; p.outMode = 1; p.partStride = 2097152;
      p.cSB = 1048576; p.cSH = 128;
      p.cOsR = 1024; p.cOsC = 1;
      gemm_nt<<<dim3(4, 8, 16), 256, 0, stream>>>(p);
    }
    reduce_split<<<2048, 256, 0, stream>>>(parts, 4, 2097152, xih, 2097152);
  }

  // out = xi @ Wo^T  (fp32 out)
  {
    GemmParams p{};
    p.A = xih; p.lda = 1024;
    p.B = wo16; p.ldb = 1024;
    p.K = 1024;
    p.C32 = (float*)d_out; p.outMode = 1;
    p.cOsR = 2048; p.cOsC = 1;
    gemm_nt<<<dim3(16, 16, 1), 256, 0, stream>>>(p);
  }
}

// Round 9
// 478.845 us; speedup vs baseline: 2.3072x; 1.0310x over previous
//
#include <hip/hip_runtime.h>

typedef _Float16 half8 __attribute__((ext_vector_type(8)));
typedef _Float16 hv4 __attribute__((ext_vector_type(4)));
typedef float fv4 __attribute__((ext_vector_type(4)));

typedef __attribute__((address_space(3))) unsigned lds_u32;
typedef const __attribute__((address_space(1))) unsigned glb_u32;

// async global->LDS, 16B per lane; dst is wave-uniform base, HW adds lane*16B
__device__ __forceinline__ void gll16(const void* g, void* l) {
  __builtin_amdgcn_global_load_lds((glb_u32*)g, (lds_u32*)l, 16, 0, 0);
}

// ---------------------------------------------------------------- LayerNorm
__global__ __launch_bounds__(256) void ln_rows(const float* __restrict__ in,
                                               const float* __restrict__ g,
                                               const float* __restrict__ bb,
                                               _Float16* __restrict__ out, int ncols) {
  __shared__ float sm[8];
  int row = blockIdx.x, t = threadIdx.x;
  const float* rp = in + (size_t)row * ncols;
  int nv = ncols >> 10;
  fv4 v[2];
  float s1 = 0.f, s2 = 0.f;
#pragma unroll
  for (int c = 0; c < 2; ++c)
    if (c < nv) {
      v[c] = *(const fv4*)(rp + c * 1024 + t * 4);
#pragma unroll
      for (int j = 0; j < 4; ++j) { s1 += v[c][j]; s2 += v[c][j] * v[c][j]; }
    }
#pragma unroll
  for (int off = 32; off > 0; off >>= 1) { s1 += __shfl_xor(s1, off, 64); s2 += __shfl_xor(s2, off, 64); }
  int w = t >> 6;
  if ((t & 63) == 0) { sm[w] = s1; sm[4 + w] = s2; }
  __syncthreads();
  s1 = sm[0] + sm[1] + sm[2] + sm[3];
  s2 = sm[4] + sm[5] + sm[6] + sm[7];
  float inv = 1.0f / (float)ncols;
  float mu = s1 * inv;
  float var = s2 * inv - mu * mu;
  float rstd = rsqrtf(var + 1e-5f);
#pragma unroll
  for (int c = 0; c < 2; ++c)
    if (c < nv) {
      int col = c * 1024 + t * 4;
      fv4 gg = *(const fv4*)(g + col);
      fv4 bv = *(const fv4*)(bb + col);
      hv4 o;
#pragma unroll
      for (int j = 0; j < 4; ++j) o[j] = (_Float16)(((v[c][j] - mu) * rstd) * gg[j] + bv[j]);
      *(hv4*)(out + (size_t)row * ncols + col) = o;
    }
}

// ---------------------------------------------------------------- fp32 -> fp16 cast
__global__ __launch_bounds__(256) void cast_f16(const float* __restrict__ in,
                                                _Float16* __restrict__ out, int n) {
  int i = (blockIdx.x * 256 + threadIdx.x) << 2;
  if (i < n) {
    fv4 f = *(const fv4*)(in + i);
    hv4 h;
#pragma unroll
    for (int j = 0; j < 4; ++j) h[j] = (_Float16)f[j];
    *(hv4*)(out + i) = h;
  }
}

// ---------------------------------------------------------------- sum ns partials -> fp16
__global__ __launch_bounds__(256) void reduce_split(const float* __restrict__ parts, int ns,
                                                    long long stride,
                                                    _Float16* __restrict__ hi, int n) {
  int i = (blockIdx.x * 256 + threadIdx.x) << 2;
  if (i < n) {
    fv4 s = *(const fv4*)(parts + i);
    for (int j = 1; j < ns; ++j) {
      fv4 v = *(const fv4*)(parts + (size_t)j * stride + i);
      s += v;
    }
    hv4 h;
#pragma unroll
    for (int j = 0; j < 4; ++j) h[j] = (_Float16)s[j];
    *(hv4*)(hi + i) = h;
  }
}

// ---------------------------------------------------------------- entmax-1.5: tau solve only
// One wave per score row (2048 fp16). Michelot exact support iteration from superset
// S0={x>-1}; after count <=512 survivors are compacted to LDS and iterated cheaply.
// Outputs c = m/2 + tau per row so that w = (max(0, s/2 - c))^2 (applied in the w@V GEMM).
__global__ __launch_bounds__(256) void entmax_c(const _Float16* __restrict__ scores,
                                                float* __restrict__ crow) {
  __shared__ float comp[4][512];
  int wid = threadIdx.x >> 6;
  int row = blockIdx.x * 4 + wid;
  int l = threadIdx.x & 63;
  unsigned long long lmask = (1ull << l) - 1ull;
  const half8* sp = (const half8*)(scores + (size_t)row * 2048);
  half8 hx[4];
#pragma unroll
  for (int i = 0; i < 4; ++i) hx[i] = sp[i * 64 + l];
  fv4 x[8];
#pragma unroll
  for (int i = 0; i < 4; ++i)
#pragma unroll
    for (int j = 0; j < 8; ++j) x[i * 2 + (j >> 2)][j & 3] = (float)hx[i][j];
  float m = x[0][0];
#pragma unroll
  for (int i = 0; i < 8; ++i)
#pragma unroll
    for (int j = 0; j < 4; ++j) m = fmaxf(m, x[i][j]);
#pragma unroll
  for (int off = 32; off > 0; off >>= 1) m = fmaxf(m, __shfl_xor(m, off, 64));
#pragma unroll
  for (int i = 0; i < 8; ++i)
#pragma unroll
    for (int j = 0; j < 4; ++j) x[i][j] = (x[i][j] - m) * 0.5f;

  float tau = -1.0f;
  bool fixed = false;
  int cnti = 2048;
  // phase 1: full-register scans until support fits in the compaction buffer
  for (int it = 0; it < 6 && !fixed; ++it) {
    float s1 = 0.f, s2 = 0.f;
    cnti = 0;
#pragma unroll
    for (int i = 0; i < 8; ++i)
#pragma unroll
      for (int j = 0; j < 4; ++j) {
        bool a = x[i][j] > tau;
        cnti += (int)__builtin_popcountll(__ballot(a));
        float sel = a ? x[i][j] : 0.f;
        s1 += sel;
        s2 = fmaf(sel, sel, s2);
      }
#pragma unroll
    for (int off = 32; off > 0; off >>= 1) {
      s1 += __shfl_xor(s1, off, 64);
      s2 += __shfl_xor(s2, off, 64);
    }
    float cnt = (float)cnti;
    float mean = s1 / cnt;
    float ss = s2 - s1 * mean;
    float nt = mean - sqrtf(fmaxf((1.0f - ss) / cnt, 0.0f));
    if (nt == tau) fixed = true;
    else tau = nt;
    if (cnti <= 512) break;
  }
  if (!fixed) {
    if (cnti <= 512) {
      // compact survivors {x > tau} into LDS (count <= cnti <= 512)
      int base = 0;
#pragma unroll
      for (int i = 0; i < 8; ++i)
#pragma unroll
        for (int j = 0; j < 4; ++j) {
          bool a = x[i][j] > tau;
          unsigned long long mk = __ballot(a);
          if (a) comp[wid][base + (int)__builtin_popcountll(mk & lmask)] = x[i][j];
          base += (int)__builtin_popcountll(mk);
        }
      float y[8];
#pragma unroll
      for (int r = 0; r < 8; ++r) {
        int idx = r * 64 + l;
        y[r] = (idx < base) ? comp[wid][idx] : -2.0f;  // sentinel < -1 <= tau
      }
      for (int it = 0; it < 10 && !fixed; ++it) {
        float s1 = 0.f, s2 = 0.f;
        int c = 0;
#pragma unroll
        for (int r = 0; r < 8; ++r) {
          bool a = y[r] > tau;
          c += (int)__builtin_popcountll(__ballot(a));
          float sel = a ? y[r] : 0.f;
          s1 += sel;
          s2 = fmaf(sel, sel, s2);
        }
#pragma unroll
        for (int off = 32; off > 0; off >>= 1) {
          s1 += __shfl_xor(s1, off, 64);
          s2 += __shfl_xor(s2, off, 64);
        }
        float cnt = (float)c;
        float mean = s1 / cnt;
        float ss = s2 - s1 * mean;
        float nt = mean - sqrtf(fmaxf((1.0f - ss) / cnt, 0.0f));
        if (nt == tau) fixed = true;
        else tau = nt;
      }
    } else {
      for (int it = 0; it < 8 && !fixed; ++it) {
        float s1 = 0.f, s2 = 0.f;
        int c = 0;
#pragma unroll
        for (int i = 0; i < 8; ++i)
#pragma unroll
          for (int j = 0; j < 4; ++j) {
            bool a = x[i][j] > tau;
            c += (int)__builtin_popcountll(__ballot(a));
            float sel = a ? x[i][j] : 0.f;
            s1 += sel;
            s2 = fmaf(sel, sel, s2);
          }
#pragma unroll
        for (int off = 32; off > 0; off >>= 1) {
          s1 += __shfl_xor(s1, off, 64);
          s2 += __shfl_xor(s2, off, 64);
        }
        float cnt = (float)c;
        float mean = s1 / cnt;
        float ss = s2 - s1 * mean;
        float nt = mean - sqrtf(fmaxf((1.0f - ss) / cnt, 0.0f));
        if (nt == tau) fixed = true;
        else tau = nt;
      }
    }
  }

  if (l == 0) crow[row] = 0.5f * m + tau;
}

// ---------------------------------------------------------------- generic NT GEMM
// C[M,N] = alpha * A[M,K] @ B[N,K]^T.  128x128 tile, 4 waves, 4x4 16x16x32 f16 MFMA.
// AMODE 0: A fp16, async gll16 staging (LDS stride 32).
// AMODE 1: A = fp16 scores + crow; staging applies w = (max(0, s/2 - c))^2 with packed
//          fp16 vector ops (VGPR->LDS, stride 40 to spread banks).
// nsplit>1: blockIdx.x = ntile*nsplit + kchunk; partial fp32 out at C32 + ks*partStride.
// dual: blockIdx.z selects job {B,outMode} vs {B2,outModeB}.
// outMode 0: fp16   1: fp32
struct GemmParams {
  const _Float16 *A, *B, *B2;
  const float* crow;
  _Float16 *C16, *C16b;
  float* C32;
  const float* log_beta;
  int K, lda, ldb;
  long long aSB, aSH, bSH;
  long long crowSB, crowSH;
  long long cSB, cSH, cOsR, cOsC;
  long long cOsRb, cOsCb;
  long long partStride;
  int alphaMode, outMode, outModeB, nsplit, dual;
};

template <int AMODE>
__global__ __launch_bounds__(256) void gemm_nt(GemmParams p) {
  constexpr int AST = AMODE ? 40 : 32;
  __shared__ __align__(16) _Float16 As[128 * AST];
  __shared__ __align__(16) _Float16 Bs[128 * 32];
  int t = threadIdx.x;
  int m0 = blockIdx.y * 128;
  int bx = blockIdx.x, n0, kbeg, kend, ks = 0;
  if (p.nsplit > 1) {
    ks = bx % p.nsplit;
    n0 = (bx / p.nsplit) * 128;
    int kl = p.K / p.nsplit;
    kbeg = ks * kl;
    kend = kbeg + kl;
  } else {
    n0 = bx * 128;
    kbeg = 0;
    kend = p.K;
  }
  int z = blockIdx.z, bidx, h, job = 0;
  if (p.dual) { job = z; bidx = 0; h = 0; }
  else { bidx = z >> 3; h = z & 7; }
  const _Float16* pA = p.A + bidx * p.aSB + h * p.aSH;
  const _Float16* pB = (job ? p.B2 : p.B) + h * p.bSH;
  const float* pc = AMODE ? p.crow + bidx * p.crowSB + h * p.crowSH : nullptr;

  fv4 acc[4][4] = {};
  int wv = t >> 6, l = t & 63, quad = l >> 4, lr = l & 15;
  int wm = (wv >> 1) * 64, wn = (wv & 1) * 64;
  int rl = l >> 2, cl = (l & 3) * 8;  // lane row-in-16 / halves offset for staging

  for (int k0 = kbeg; k0 < kend; k0 += 32) {
#pragma unroll
    for (int v = 0; v < 2; ++v) {
      int rb = wv * 16 + v * 64;  // wave-uniform row base
      int r = rb + rl;
      size_t aOff = (size_t)(m0 + r) * p.lda + k0 + cl;
      size_t bOff = (size_t)(n0 + r) * p.ldb + k0 + cl;
      if (AMODE == 0) {
        gll16(pA + aOff, &As[rb * 32]);
      } else {
        half8 s8 = *(const half8*)(pA + aOff);
        _Float16 c0 = (_Float16)pc[m0 + r];
        half8 d = s8 * (_Float16)0.5f - c0;            // v_pk_fma/add_f16 (scalar splat)
        d = __builtin_elementwise_max(d, (half8)(0));  // v_pk_max_f16
        half8 w8 = d * d;                              // v_pk_mul_f16
        *(half8*)&As[r * AST + cl] = w8;
      }
      gll16(pB + bOff, &Bs[rb * 32]);
    }
    __syncthreads();  // drains vmcnt + lgkmcnt: staging complete
    half8 ah[4], bh[4];
#pragma unroll
    for (int mi = 0; mi < 4; ++mi) ah[mi] = *(const half8*)&As[(wm + mi * 16 + lr) * AST + quad * 8];
#pragma unroll
    for (int ni = 0; ni < 4; ++ni) bh[ni] = *(const half8*)&Bs[(wn + ni * 16 + lr) * 32 + quad * 8];
#pragma unroll
    for (int mi = 0; mi < 4; ++mi)
#pragma unroll
      for (int ni = 0; ni < 4; ++ni)
        acc[mi][ni] = __builtin_amdgcn_mfma_f32_16x16x32_f16(ah[mi], bh[ni], acc[mi][ni], 0, 0, 0);
    __syncthreads();
  }

  float alpha = p.alphaMode ? __expf(p.log_beta[h]) : 1.0f;
  int om = (p.dual && job) ? p.outModeB : p.outMode;
  _Float16* c16 = (p.dual && job) ? p.C16b : p.C16;
  long long osR = (p.dual && job) ? p.cOsRb : p.cOsR;
  long long osC = (p.dual && job) ? p.cOsCb : p.cOsC;
  float* c32 = p.C32 + (p.nsplit > 1 ? (long long)ks * p.partStride : 0);
  long long cOff = (long long)bidx * p.cSB + (long long)h * p.cSH;
#pragma unroll
  for (int mi = 0; mi < 4; ++mi)
#pragma unroll
    for (int ni = 0; ni < 4; ++ni) {
      int row = m0 + wm + mi * 16 + quad * 4;
      int col = n0 + wn + ni * 16 + lr;
#pragma unroll
      for (int r = 0; r < 4; ++r) {
        float val = acc[mi][ni][r] * alpha;
        long long idx = cOff + (long long)(row + r) * osR + (long long)col * osC;
        if (om == 1) c32[idx] = val;
        else c16[idx] = (_Float16)val;
      }
    }
}

// ---------------------------------------------------------------- host
extern "C" void kernel_launch(void* const* d_in, const int* in_sizes, int n_in,
                              void* d_out, int out_size, void* d_ws, size_t ws_size,
                              hipStream_t stream) {
  const float* hidden = (const float*)d_in[0];   // (2,1024,2048)
  const float* memory = (const float*)d_in[1];   // (2048,1024)
  const float* Wq = (const float*)d_in[2];       // (1024,2048)
  const float* Wk = (const float*)d_in[3];       // (1024,1024)
  const float* Wv = (const float*)d_in[4];       // (1024,1024)
  const float* Wo = (const float*)d_in[5];       // (2048,1024)
  const float* log_beta = (const float*)d_in[6]; // (8,)
  const float* g_state = (const float*)d_in[7];
  const float* b_state = (const float*)d_in[8];
  const float* g_mem = (const float*)d_in[9];
  const float* b_mem = (const float*)d_in[10];

  char* w = (char*)d_ws;
  auto alloc = [&](size_t bytes) {
    char* r = w;
    w += (bytes + 255) & ~(size_t)255;
    return r;
  };
  _Float16* wq16 = (_Float16*)alloc(2097152 * 2);
  _Float16* wk16 = (_Float16*)alloc(1048576 * 2);
  _Float16* wv16 = (_Float16*)alloc(1048576 * 2);
  _Float16* wo16 = (_Float16*)alloc(2097152 * 2);
  _Float16* lnh16 = (_Float16*)alloc(4194304 * 2);
  _Float16* mn16 = (_Float16*)alloc(2097152 * 2);
  _Float16* kph = (_Float16*)alloc(2097152 * 2);   // K proj (n, h*128+d)
  _Float16* vt16 = (_Float16*)alloc(2097152 * 2);  // V^T (h*128+d, n)
  _Float16* xih = (_Float16*)alloc(2097152 * 2);   // xi (b*S+s, h*128+d)
  float* parts = (float*)alloc((size_t)8 * 2097152 * 4);        // split-K partials
  _Float16* scores16 = (_Float16*)alloc((size_t)33554432 * 2);  // (b,h,s,n) fp16
  float* crow = (float*)alloc(16384 * 4);                       // per-row c = m/2 + tau

  ln_rows<<<2048, 256, 0, stream>>>(hidden, g_state, b_state, lnh16, 2048);
  ln_rows<<<2048, 256, 0, stream>>>(memory, g_mem, b_mem, mn16, 1024);
  cast_f16<<<2048, 256, 0, stream>>>(Wq, wq16, 2097152);
  cast_f16<<<1024, 256, 0, stream>>>(Wk, wk16, 1048576);
  cast_f16<<<1024, 256, 0, stream>>>(Wv, wv16, 1048576);
  cast_f16<<<2048, 256, 0, stream>>>(Wo, wo16, 2097152);

  // Q = ln(hidden) @ Wq^T  (split-K=2 partials -> reduce -> xi fp16)
  {
    GemmParams p{};
    p.A = lnh16; p.lda = 2048;
    p.B = wq16; p.ldb = 2048;
    p.K = 2048; p.nsplit = 2;
    p.C32 = parts; p.outMode = 1; p.partStride = 2097152;
    p.cOsR = 1024; p.cOsC = 1;
    gemm_nt<0><<<dim3(16, 16, 1), 256, 0, stream>>>(p);
    reduce_split<<<2048, 256, 0, stream>>>(parts, 2, 2097152, xih, 2097152);
  }
  // K & V projections in one dual-job launch (both plain fp16)
  {
    GemmParams p{};
    p.A = mn16; p.lda = 1024;
    p.B = wk16; p.B2 = wv16; p.ldb = 1024;
    p.K = 1024; p.dual = 1;
    p.C16 = kph; p.outMode = 0; p.cOsR = 1024; p.cOsC = 1;
    p.C16b = vt16; p.outModeB = 0; p.cOsRb = 1; p.cOsCb = 2048;
    gemm_nt<0><<<dim3(8, 16, 2), 256, 0, stream>>>(p);
  }

  for (int step = 0; step < 3; ++step) {
    // scores = beta_h * xi @ K^T  (plain fp16, fp16 out)
    {
      GemmParams p{};
      p.A = xih;
      p.lda = 1024; p.aSB = 1048576; p.aSH = 128;
      p.B = kph; p.ldb = 1024; p.bSH = 128;
      p.K = 128;
      p.alphaMode = 1; p.log_beta = log_beta;
      p.C16 = scores16; p.outMode = 0;
      p.cSB = 16777216; p.cSH = 2097152;
      p.cOsR = 2048; p.cOsC = 1;
      gemm_nt<0><<<dim3(16, 8, 16), 256, 0, stream>>>(p);
    }
    entmax_c<<<4096, 256, 0, stream>>>(scores16, crow);
    // xi = w @ V  (w fused in staging from scores+crow, split-K=4 -> reduce)
    {
      GemmParams p{};
      p.A = scores16; p.crow = crow;
      p.lda = 2048; p.aSB = 16777216; p.aSH = 2097152;
      p.crowSB = 8192; p.crowSH = 1024;
      p.B = vt16; p.ldb = 2048; p.bSH = 262144;
      p.K = 2048; p.nsplit = 4;
      p.C32 = parts; p.outMode = 1; p.partStride = 2097152;
      p.cSB = 1048576; p.cSH = 128;
      p.cOsR = 1024; p.cOsC = 1;
      gemm_nt<1><<<dim3(4, 8, 16), 256, 0, stream>>>(p);
    }
    reduce_split<<<2048, 256, 0, stream>>>(parts, 4, 2097152, xih, 2097152);
  }

  // out = xi @ Wo^T  (fp32 out)
  {
    GemmParams p{};
    p.A = xih; p.lda = 1024;
    p.B = wo16; p.ldb = 1024;
    p.K = 1024;
    p.C32 = (float*)d_out; p.outMode = 1;
    p.cOsR = 2048; p.cOsC = 1;
    gemm_nt<0><<<dim3(16, 16, 1), 256, 0, stream>>>(p);
  }
}